// Round 2
// baseline (1948.624 us; speedup 1.0000x reference)
//
#include <hip/hip_runtime.h>
#include <math.h>

#define NVOX 120000
#define CDIM 128
#define NWIN 5000
#define HWPIX 102400
// padded canvas: 322 x 322 cells per batch
#define PW 322
#define PCELLS 103684

typedef __attribute__((ext_vector_type(8))) short short8;
typedef __attribute__((ext_vector_type(4))) float f32x4;

__device__ __forceinline__ unsigned short f2bf(float f) {
  unsigned u = __float_as_uint(f);
  return (unsigned short)((u + 0x7FFFu + ((u >> 16) & 1u)) >> 16);
}
__device__ __forceinline__ unsigned pack2(float a, float b) {
  return (unsigned)f2bf(a) | ((unsigned)f2bf(b) << 16);
}
__device__ __forceinline__ void unpack2(unsigned u, float& a, float& b) {
  a = __uint_as_float(u << 16);
  b = __uint_as_float(u & 0xFFFF0000u);
}

// ============================================================================
// MFMA core: block = 256 thr = 4 waves. Block tile M=64 x N=128, K staged 128.
// Wave wv: rows 32*(wv>>1)+{0..31} (2 m-tiles), cols 64*(wv&1)+{0..63} (4 n-tiles).
// LDS pitch 136 bf16 (272 B). A-frag: A[m=lane&15][k=quad*8+j];
// B-frag: W[n=lane&15][k=quad*8+j] (W is [N][K]). C/D: col=lane&15, row=quad*4+reg.
// ============================================================================
__device__ __forceinline__ void mma128(const short* __restrict__ As,
                                       const short* __restrict__ Ws,
                                       int aoff, int boff, f32x4 acc[2][4]) {
#pragma unroll
  for (int kc = 0; kc < 4; ++kc) {
    short8 a0 = *(const short8*)(As + aoff + kc * 32);
    short8 a1 = *(const short8*)(As + aoff + 136 * 16 + kc * 32);
#pragma unroll
    for (int nt = 0; nt < 4; ++nt) {
      short8 b = *(const short8*)(Ws + boff + nt * 136 * 16 + kc * 32);
      acc[0][nt] = __builtin_amdgcn_mfma_f32_16x16x32_bf16(a0, b, acc[0][nt], 0, 0, 0);
      acc[1][nt] = __builtin_amdgcn_mfma_f32_16x16x32_bf16(a1, b, acc[1][nt], 0, 0, 0);
    }
  }
}

// ---------------------------------------------------------------------------
__global__ __launch_bounds__(256) void cvt_kernel(const float* __restrict__ src,
                                                  unsigned short* __restrict__ dst, int n4) {
  int i = blockIdx.x * 256 + threadIdx.x;
  if (i >= n4) return;
  float4 v = ((const float4*)src)[i];
  uint2 o; o.x = pack2(v.x, v.y); o.y = pack2(v.z, v.w);
  ((uint2*)dst)[i] = o;
}

__global__ __launch_bounds__(256) void cvtT_kernel(const float* __restrict__ w,
                                                   unsigned short* __restrict__ wT) {
  int idx = blockIdx.x * 256 + threadIdx.x;
  if (idx >= 2 * 9 * 128 * 128) return;
  int ci = idx & 127;
  int co = (idx >> 7) & 127;
  int tap = (idx >> 14) % 9;
  int conv = idx / (9 * 16384);
  wT[idx] = f2bf(w[((size_t)(conv * 128 + co) * 128 + ci) * 9 + tap]);
}

// ---------------------------------------------------------------------------
__global__ __launch_bounds__(256) void qkv_kernel(
    const unsigned short* __restrict__ x, const float* __restrict__ pos,
    const int* __restrict__ ind, const unsigned short* __restrict__ ipwB,
    const float* __restrict__ ipb, unsigned short* __restrict__ qb,
    unsigned short* __restrict__ kb, unsigned short* __restrict__ vb) {
  __shared__ __align__(16) char ldsraw[52224];
  short* As = (short*)ldsraw;             // [64][136]
  short* Ws = (short*)(ldsraw + 17408);   // [128][136]
  const int t = threadIdx.x;
  const int lane = t & 63, wv = t >> 6;
  const int l15 = lane & 15, quad = lane >> 4;
  const int rbase = 32 * (wv >> 1), cbase = 64 * (wv & 1);
  const int mbase = blockIdx.x * 64;
  const int sec = blockIdx.y;
  f32x4 acc[2][4];
#pragma unroll
  for (int m = 0; m < 2; ++m)
#pragma unroll
    for (int n = 0; n < 4; ++n) acc[m][n] = (f32x4){0.f, 0.f, 0.f, 0.f};

  for (int fi = t; fi < 1024; fi += 256) {
    int row = fi >> 4, c8 = fi & 15;
    int vox = mbase + row;
    uint4 xv = ((const uint4*)x)[(size_t)vox * 16 + c8];
    if (sec < 2) {
      int s = ind[vox];
      const float4* pp = (const float4*)(pos + (size_t)s * 128 + c8 * 8);
      float4 p0 = pp[0], p1 = pp[1];
      float f0, f1, f2, f3, f4, f5, f6, f7;
      unpack2(xv.x, f0, f1); unpack2(xv.y, f2, f3);
      unpack2(xv.z, f4, f5); unpack2(xv.w, f6, f7);
      xv.x = pack2(f0 + p0.x, f1 + p0.y); xv.y = pack2(f2 + p0.z, f3 + p0.w);
      xv.z = pack2(f4 + p1.x, f5 + p1.y); xv.w = pack2(f6 + p1.z, f7 + p1.w);
    }
    *(uint4*)&As[row * 136 + c8 * 8] = xv;
  }
  for (int fi = t; fi < 2048; fi += 256) {
    int row = fi >> 4, c8 = fi & 15;
    ((uint4*)&Ws[row * 136])[c8] =
        ((const uint4*)(ipwB + (size_t)(sec * 128 + row) * 128))[c8];
  }
  __syncthreads();
  mma128(As, Ws, (rbase + l15) * 136 + quad * 8, (cbase + l15) * 136 + quad * 8, acc);
  __syncthreads();

  short* Ybf = (short*)ldsraw;  // [64][136]
#pragma unroll
  for (int nt = 0; nt < 4; ++nt) {
    int col = cbase + nt * 16 + l15;
    float bias = ipb[sec * 128 + col];
#pragma unroll
    for (int mt = 0; mt < 2; ++mt)
#pragma unroll
      for (int r = 0; r < 4; ++r)
        Ybf[(rbase + mt * 16 + quad * 4 + r) * 136 + col] =
            (short)f2bf(acc[mt][nt][r] + bias);
  }
  __syncthreads();
  unsigned short* dst = (sec == 0) ? qb : ((sec == 1) ? kb : vb);
  for (int fi = t; fi < 1024; fi += 256) {
    int row = fi >> 4, c8 = fi & 15;
    int s = ind[mbase + row];
    int slot = (s / 36) * 24 + (s % 36);
    ((uint4*)dst)[(size_t)slot * 16 + c8] = ((const uint4*)&Ybf[row * 136])[c8];
  }
}

// ---------------------------------------------------------------------------
__global__ __launch_bounds__(256) void attn_kernel(
    unsigned short* __restrict__ qb, const unsigned short* __restrict__ kb,
    const unsigned short* __restrict__ vb) {
  __shared__ float lds[14112];
  float* Qs = lds;          // [24][132]
  float* Ks = lds + 3168;
  float* Vs = lds + 6336;
  float* S = lds + 9504;    // [8][24][24]
  const int t = threadIdx.x;
  const size_t base = (size_t)blockIdx.x * 3072;
  for (int fi = t; fi < 1152; fi += 256) {
    int arr = fi / 384, rem = fi % 384;
    int row = rem >> 4, c8 = rem & 15;
    const unsigned short* src = arr == 0 ? qb : (arr == 1 ? kb : vb);
    uint4 raw = ((const uint4*)(src + base))[row * 16 + c8];
    float* dl = lds + arr * 3168 + row * 132 + c8 * 8;
    unpack2(raw.x, dl[0], dl[1]); unpack2(raw.y, dl[2], dl[3]);
    unpack2(raw.z, dl[4], dl[5]); unpack2(raw.w, dl[6], dl[7]);
  }
  __syncthreads();
  for (int idx = t; idx < 4608; idx += 256) {
    int hh = idx / 576, rem = idx % 576;
    int qq = rem / 24, kk = rem % 24;
    const float* qp = &Qs[qq * 132 + hh * 16];
    const float* kp = &Ks[kk * 132 + hh * 16];
    float s = 0.f;
#pragma unroll
    for (int d = 0; d < 16; ++d) s = fmaf(qp[d], kp[d], s);
    S[idx] = s * 0.25f;
  }
  __syncthreads();
  if (t < 192) {
    float* rowp = &S[t * 24];
    float m = rowp[0];
#pragma unroll
    for (int k2 = 1; k2 < 24; ++k2) m = fmaxf(m, rowp[k2]);
    float sum = 0.f;
#pragma unroll
    for (int k2 = 0; k2 < 24; ++k2) { float e = __expf(rowp[k2] - m); rowp[k2] = e; sum += e; }
    float inv = 1.f / sum;
#pragma unroll
    for (int k2 = 0; k2 < 24; ++k2) rowp[k2] *= inv;
  }
  __syncthreads();
  for (int idx = t; idx < 3072; idx += 256) {
    int hh = idx / 384, rem = idx % 384;
    int qq = rem >> 4, dd = rem & 15;
    const float* pp = &S[hh * 576 + qq * 24];
    const float* vp = &Vs[hh * 16 + dd];
    float o = 0.f;
#pragma unroll
    for (int k2 = 0; k2 < 24; ++k2) o = fmaf(pp[k2], vp[k2 * 132], o);
    qb[base + qq * 128 + hh * 16 + dd] = f2bf(o);
  }
}

// ---------------------------------------------------------------------------
__global__ __launch_bounds__(256) void outln_kernel(
    const unsigned short* __restrict__ o, const int* __restrict__ ind,
    const unsigned short* __restrict__ opwB, const float* __restrict__ opb,
    const unsigned short* __restrict__ xres, const float* __restrict__ lnw,
    const float* __restrict__ lnb, unsigned short* __restrict__ hout) {
  __shared__ __align__(16) char ldsraw[52224];
  short* As = (short*)ldsraw;
  short* Ws = (short*)(ldsraw + 17408);
  const int t = threadIdx.x;
  const int lane = t & 63, wv = t >> 6;
  const int l15 = lane & 15, quad = lane >> 4;
  const int rbase = 32 * (wv >> 1), cbase = 64 * (wv & 1);
  const int mbase = blockIdx.x * 64;
  f32x4 acc[2][4];
#pragma unroll
  for (int m = 0; m < 2; ++m)
#pragma unroll
    for (int n = 0; n < 4; ++n) acc[m][n] = (f32x4){0.f, 0.f, 0.f, 0.f};

  for (int fi = t; fi < 1024; fi += 256) {
    int row = fi >> 4, c8 = fi & 15;
    int s = ind[mbase + row];
    int slot = (s / 36) * 24 + (s % 36);
    *(uint4*)&As[row * 136 + c8 * 8] = ((const uint4*)o)[(size_t)slot * 16 + c8];
  }
  for (int fi = t; fi < 2048; fi += 256) {
    int row = fi >> 4, c8 = fi & 15;
    ((uint4*)&Ws[row * 136])[c8] = ((const uint4*)(opwB + (size_t)row * 128))[c8];
  }
  __syncthreads();
  mma128(As, Ws, (rbase + l15) * 136 + quad * 8, (cbase + l15) * 136 + quad * 8, acc);
  __syncthreads();

  float* Yf = (float*)ldsraw;               // [64][132]
  float* p1 = (float*)(ldsraw + 33792);
  float* p2 = (float*)(ldsraw + 34816);
  float* Ms = (float*)(ldsraw + 35840);
  float* Rs = (float*)(ldsraw + 36096);
#pragma unroll
  for (int nt = 0; nt < 4; ++nt) {
    int col = cbase + nt * 16 + l15;
    float bias = opb[col];
#pragma unroll
    for (int mt = 0; mt < 2; ++mt)
#pragma unroll
      for (int r = 0; r < 4; ++r)
        Yf[(rbase + mt * 16 + quad * 4 + r) * 132 + col] = acc[mt][nt][r] + bias;
  }
  __syncthreads();
  for (int fi = t; fi < 1024; fi += 256) {
    int row = fi >> 4, c8 = fi & 15;
    uint4 xv = ((const uint4*)xres)[(size_t)(mbase + row) * 16 + c8];
    float* yp = &Yf[row * 132 + c8 * 8];
    float a, b;
    unpack2(xv.x, a, b); yp[0] += a; yp[1] += b;
    unpack2(xv.y, a, b); yp[2] += a; yp[3] += b;
    unpack2(xv.z, a, b); yp[4] += a; yp[5] += b;
    unpack2(xv.w, a, b); yp[6] += a; yp[7] += b;
  }
  __syncthreads();
  {
    int r = t & 63, g = t >> 6;
    float s = 0.f, s2 = 0.f;
    for (int c = g * 32; c < g * 32 + 32; ++c) { float v = Yf[r * 132 + c]; s += v; s2 += v * v; }
    p1[g * 64 + r] = s; p2[g * 64 + r] = s2;
  }
  __syncthreads();
  if (t < 64) {
    float s = p1[t] + p1[64 + t] + p1[128 + t] + p1[192 + t];
    float s2 = p2[t] + p2[64 + t] + p2[128 + t] + p2[192 + t];
    float m = s * (1.f / 128.f);
    float var = s2 * (1.f / 128.f) - m * m;
    Ms[t] = m; Rs[t] = rsqrtf(var + 1e-5f);
  }
  __syncthreads();
  for (int fi = t; fi < 1024; fi += 256) {
    int row = fi >> 4, c8 = fi & 15;
    float m = Ms[row], rr = Rs[row];
    const float* yp = &Yf[row * 132 + c8 * 8];
    uint4 ov;
    float v0, v1;
#define LNPAIR(J, FLD) \
    v0 = (yp[2*J] - m) * rr * lnw[c8*8+2*J] + lnb[c8*8+2*J]; \
    v1 = (yp[2*J+1] - m) * rr * lnw[c8*8+2*J+1] + lnb[c8*8+2*J+1]; \
    ov.FLD = pack2(v0, v1);
    LNPAIR(0, x) LNPAIR(1, y) LNPAIR(2, z) LNPAIR(3, w)
#undef LNPAIR
    ((uint4*)hout)[(size_t)(mbase + row) * 16 + c8] = ov;
  }
}

// ---------------------------------------------------------------------------
__global__ __launch_bounds__(256) void ffn1_kernel(
    const unsigned short* __restrict__ h, const unsigned short* __restrict__ w1B,
    const float* __restrict__ b1, unsigned short* __restrict__ ff) {
  __shared__ __align__(16) char ldsraw[52224];
  short* As = (short*)ldsraw;
  short* Ws = (short*)(ldsraw + 17408);
  const int t = threadIdx.x;
  const int lane = t & 63, wv = t >> 6;
  const int l15 = lane & 15, quad = lane >> 4;
  const int rbase = 32 * (wv >> 1), cbase = 64 * (wv & 1);
  const int mbase = blockIdx.x * 64;
  const int by = blockIdx.y;
  f32x4 acc[2][4];
#pragma unroll
  for (int m = 0; m < 2; ++m)
#pragma unroll
    for (int n = 0; n < 4; ++n) acc[m][n] = (f32x4){0.f, 0.f, 0.f, 0.f};

  for (int fi = t; fi < 1024; fi += 256) {
    int row = fi >> 4, c8 = fi & 15;
    *(uint4*)&As[row * 136 + c8 * 8] = ((const uint4*)h)[(size_t)(mbase + row) * 16 + c8];
  }
  for (int fi = t; fi < 2048; fi += 256) {
    int row = fi >> 4, c8 = fi & 15;
    ((uint4*)&Ws[row * 136])[c8] =
        ((const uint4*)(w1B + (size_t)(by * 128 + row) * 128))[c8];
  }
  __syncthreads();
  mma128(As, Ws, (rbase + l15) * 136 + quad * 8, (cbase + l15) * 136 + quad * 8, acc);
  __syncthreads();

  short* Ybf = (short*)ldsraw;
#pragma unroll
  for (int nt = 0; nt < 4; ++nt) {
    int col = cbase + nt * 16 + l15;
    float bias = b1[by * 128 + col];
#pragma unroll
    for (int mt = 0; mt < 2; ++mt)
#pragma unroll
      for (int r = 0; r < 4; ++r) {
        float v = acc[mt][nt][r] + bias;
        float g = 0.5f * v * (1.f + erff(v * 0.70710678f));
        Ybf[(rbase + mt * 16 + quad * 4 + r) * 136 + col] = (short)f2bf(g);
      }
  }
  __syncthreads();
  for (int fi = t; fi < 1024; fi += 256) {
    int row = fi >> 4, c8 = fi & 15;
    ((uint4*)ff)[(size_t)(mbase + row) * 32 + by * 16 + c8] =
        ((const uint4*)&Ybf[row * 136])[c8];
  }
}

// ---------------------------------------------------------------------------
__global__ __launch_bounds__(256) void ffn2_kernel(
    const unsigned short* __restrict__ ff, const unsigned short* __restrict__ w2B,
    const float* __restrict__ b2, const unsigned short* __restrict__ hres,
    const float* __restrict__ lnw, const float* __restrict__ lnb,
    unsigned short* __restrict__ xout) {
  __shared__ __align__(16) char ldsraw[52224];
  short* As = (short*)ldsraw;
  short* Ws = (short*)(ldsraw + 17408);
  const int t = threadIdx.x;
  const int lane = t & 63, wv = t >> 6;
  const int l15 = lane & 15, quad = lane >> 4;
  const int rbase = 32 * (wv >> 1), cbase = 64 * (wv & 1);
  const int mbase = blockIdx.x * 64;
  f32x4 acc[2][4];
#pragma unroll
  for (int m = 0; m < 2; ++m)
#pragma unroll
    for (int n = 0; n < 4; ++n) acc[m][n] = (f32x4){0.f, 0.f, 0.f, 0.f};

  for (int k2 = 0; k2 < 2; ++k2) {
    if (k2) __syncthreads();
    for (int fi = t; fi < 1024; fi += 256) {
      int row = fi >> 4, c8 = fi & 15;
      *(uint4*)&As[row * 136 + c8 * 8] =
          ((const uint4*)ff)[(size_t)(mbase + row) * 32 + k2 * 16 + c8];
    }
    for (int fi = t; fi < 2048; fi += 256) {
      int row = fi >> 4, c8 = fi & 15;
      ((uint4*)&Ws[row * 136])[c8] =
          ((const uint4*)(w2B + (size_t)row * 256 + k2 * 128))[c8];
    }
    __syncthreads();
    mma128(As, Ws, (rbase + l15) * 136 + quad * 8, (cbase + l15) * 136 + quad * 8, acc);
  }
  __syncthreads();

  float* Yf = (float*)ldsraw;
  float* p1 = (float*)(ldsraw + 33792);
  float* p2 = (float*)(ldsraw + 34816);
  float* Ms = (float*)(ldsraw + 35840);
  float* Rs = (float*)(ldsraw + 36096);
#pragma unroll
  for (int nt = 0; nt < 4; ++nt) {
    int col = cbase + nt * 16 + l15;
    float bias = b2[col];
#pragma unroll
    for (int mt = 0; mt < 2; ++mt)
#pragma unroll
      for (int r = 0; r < 4; ++r)
        Yf[(rbase + mt * 16 + quad * 4 + r) * 132 + col] = acc[mt][nt][r] + bias;
  }
  __syncthreads();
  for (int fi = t; fi < 1024; fi += 256) {
    int row = fi >> 4, c8 = fi & 15;
    uint4 xv = ((const uint4*)hres)[(size_t)(mbase + row) * 16 + c8];
    float* yp = &Yf[row * 132 + c8 * 8];
    float a, b;
    unpack2(xv.x, a, b); yp[0] += a; yp[1] += b;
    unpack2(xv.y, a, b); yp[2] += a; yp[3] += b;
    unpack2(xv.z, a, b); yp[4] += a; yp[5] += b;
    unpack2(xv.w, a, b); yp[6] += a; yp[7] += b;
  }
  __syncthreads();
  {
    int r = t & 63, g = t >> 6;
    float s = 0.f, s2 = 0.f;
    for (int c = g * 32; c < g * 32 + 32; ++c) { float v = Yf[r * 132 + c]; s += v; s2 += v * v; }
    p1[g * 64 + r] = s; p2[g * 64 + r] = s2;
  }
  __syncthreads();
  if (t < 64) {
    float s = p1[t] + p1[64 + t] + p1[128 + t] + p1[192 + t];
    float s2 = p2[t] + p2[64 + t] + p2[128 + t] + p2[192 + t];
    float m = s * (1.f / 128.f);
    float var = s2 * (1.f / 128.f) - m * m;
    Ms[t] = m; Rs[t] = rsqrtf(var + 1e-5f);
  }
  __syncthreads();
  for (int fi = t; fi < 1024; fi += 256) {
    int row = fi >> 4, c8 = fi & 15;
    float m = Ms[row], rr = Rs[row];
    const float* yp = &Yf[row * 132 + c8 * 8];
    uint4 ov;
    float v0, v1;
#define LNPAIR(J, FLD) \
    v0 = (yp[2*J] - m) * rr * lnw[c8*8+2*J] + lnb[c8*8+2*J]; \
    v1 = (yp[2*J+1] - m) * rr * lnw[c8*8+2*J+1] + lnb[c8*8+2*J+1]; \
    ov.FLD = pack2(v0, v1);
    LNPAIR(0, x) LNPAIR(1, y) LNPAIR(2, z) LNPAIR(3, w)
#undef LNPAIR
    ((uint4*)xout)[(size_t)(mbase + row) * 16 + c8] = ov;
  }
}

// ---------------------------------------------------------------------------
__global__ void idx_init_kernel(int* __restrict__ idxmap) {
  int i = blockIdx.x * 256 + threadIdx.x;
  if (i < 2 * HWPIX) idxmap[i] = -1;
}

__global__ void scatter_kernel(const int* __restrict__ coors, int* __restrict__ idxmap) {
  int i = blockIdx.x * 256 + threadIdx.x;
  if (i >= NVOX) return;
  int b = coors[i * 4 + 0], y = coors[i * 4 + 2], xx = coors[i * 4 + 3];
  atomicMax(&idxmap[b * HWPIX + y * 320 + xx], i);
}

// writes PADDED canvas [b][322][322][128]; halo cells = 0
__global__ void canvas_kernel(const unsigned short* __restrict__ x,
                              const int* __restrict__ idxmap,
                              unsigned short* __restrict__ canvas) {
  int idx = blockIdx.x * 256 + threadIdx.x;
  if (idx >= 2 * PCELLS * 16) return;
  int cell = idx >> 4, c8 = idx & 15;
  int b = (cell >= PCELLS) ? 1 : 0;
  cell -= b * PCELLS;
  int yy = cell / PW, xx = cell - yy * PW;
  uint4 v = {0u, 0u, 0u, 0u};
  if (yy >= 1 && yy <= 320 && xx >= 1 && xx <= 320) {
    int vox = idxmap[b * HWPIX + (yy - 1) * 320 + (xx - 1)];
    if (vox >= 0) v = ((const uint4*)x)[(size_t)vox * 16 + c8];
  }
  ((uint4*)canvas)[idx] = v;
}

// zero the halo cells of a padded NHWC buffer (for c1out between the convs)
__global__ void border_kernel(unsigned short* __restrict__ buf) {
  int i = blockIdx.x * 256 + threadIdx.x;
  if (i >= 2 * 1284 * 16) return;
  int c8 = i & 15, j = i >> 4;
  int b = (j >= 1284) ? 1 : 0;
  j -= b * 1284;
  int cell;
  if (j < 322) cell = j;                                   // top row
  else if (j < 644) cell = 321 * PW + (j - 322);           // bottom row
  else { int j2 = j - 644; cell = (1 + (j2 >> 1)) * PW + (j2 & 1) * 321; }  // sides
  uint4 z = {0u, 0u, 0u, 0u};
  ((uint4*)buf)[((size_t)b * PCELLS + cell) * 16 + c8] = z;
}

// ---------------------------------------------------------------------------
// Conv 3x3, padded NHWC bf16 input [b][322][322][128].
// Round-0 structure (M=64 px x N=128 co, patch+weights in LDS, 52.8 KB,
// 3 blocks/CU) + T14 issue-early/write-late staging: next tap's weights and
// next dy's patch row are global-loaded into registers BEFORE the current
// tap's 32 MFMAs, ds-written after the post-MFMA barrier. The inter-barrier
// critical path is now ds_writes only (~100 cy) instead of a full global
// round-trip (~400-600 cy).
template <int NCHW_OUT>
__global__ __launch_bounds__(256) void conv_kernel(
    const unsigned short* __restrict__ in, const unsigned short* __restrict__ wTb,
    void* __restrict__ outp) {
  __shared__ __align__(16) char ldsraw[52768];
  short* patch = (short*)ldsraw;           // [66 cols][136]
  short* Wt = (short*)(ldsraw + 17952);    // [128 co][136]
  const int t = threadIdx.x;
  const int lane = t & 63, wv = t >> 6;
  const int l15 = lane & 15, quad = lane >> 4;
  const int rbase = 32 * (wv >> 1), cbase = 64 * (wv & 1);
  const int x0 = blockIdx.x * 64;
  const int y0 = blockIdx.y;               // output row, padded row = y0+1
  const int b = blockIdx.z;
  const unsigned short* inb = in + (size_t)b * PCELLS * 128;
  const int srow = t >> 4, sc8 = t & 15;   // weight staging coords

  f32x4 acc[2][4];
#pragma unroll
  for (int m = 0; m < 2; ++m)
#pragma unroll
    for (int n = 0; n < 4; ++n) acc[m][n] = (f32x4){0.f, 0.f, 0.f, 0.f};

  uint4 wreg[8];
  uint4 pp[4], px4;

  // --- prologue: load patch(dy=0) + weights(tap=0), write, one barrier ---
  {
    const uint4* src = (const uint4*)inb + ((size_t)y0 * PW + x0) * 16;
#pragma unroll
    for (int k = 0; k < 4; ++k) pp[k] = src[t + 256 * k];
    if (t < 32) px4 = src[1024 + t];
  }
#pragma unroll
  for (int i = 0; i < 8; ++i)
    wreg[i] = ((const uint4*)(wTb + (size_t)(i * 16 + srow) * 128))[sc8];
#pragma unroll
  for (int k = 0; k < 4; ++k) {
    int e = t + 256 * k;
    *(uint4*)&patch[(e >> 4) * 136 + (e & 15) * 8] = pp[k];
  }
  if (t < 32) { int e = 1024 + t; *(uint4*)&patch[(e >> 4) * 136 + (e & 15) * 8] = px4; }
#pragma unroll
  for (int i = 0; i < 8; ++i)
    *(uint4*)&Wt[(i * 16 + srow) * 136 + sc8 * 8] = wreg[i];
  __syncthreads();

#pragma unroll
  for (int tap = 0; tap < 9; ++tap) {
    const int dy = tap / 3, dx = tap % 3;
    const bool pfP = (dx == 2) && (dy < 2);   // prefetch patch for dy+1
    const bool pfW = (tap < 8);               // prefetch weights for tap+1
    if (pfP) {
      const uint4* src = (const uint4*)inb + ((size_t)(y0 + dy + 1) * PW + x0) * 16;
#pragma unroll
      for (int k = 0; k < 4; ++k) pp[k] = src[t + 256 * k];
      if (t < 32) px4 = src[1024 + t];
    }
    if (pfW) {
#pragma unroll
      for (int i = 0; i < 8; ++i)
        wreg[i] = ((const uint4*)(wTb + (size_t)((tap + 1) * 128 + i * 16 + srow) * 128))[sc8];
    }
    mma128(patch, Wt, (rbase + l15 + dx) * 136 + quad * 8,
           (cbase + l15) * 136 + quad * 8, acc);
    __syncthreads();   // all waves done reading current LDS contents
    if (pfW) {
      if (pfP) {
#pragma unroll
        for (int k = 0; k < 4; ++k) {
          int e = t + 256 * k;
          *(uint4*)&patch[(e >> 4) * 136 + (e & 15) * 8] = pp[k];
        }
        if (t < 32) { int e = 1024 + t; *(uint4*)&patch[(e >> 4) * 136 + (e & 15) * 8] = px4; }
      }
#pragma unroll
      for (int i = 0; i < 8; ++i)
        *(uint4*)&Wt[(i * 16 + srow) * 136 + sc8 * 8] = wreg[i];
      __syncthreads();
    }
  }
  // last loop iteration ends with a barrier (post-MFMA) -> LDS reuse safe

  if (NCHW_OUT) {
    float* Yf = (float*)ldsraw;  // [128 co][68 px]
#pragma unroll
    for (int nt = 0; nt < 4; ++nt) {
      int col = cbase + nt * 16 + l15;
#pragma unroll
      for (int mt = 0; mt < 2; ++mt)
#pragma unroll
        for (int r = 0; r < 4; ++r)
          Yf[col * 68 + rbase + mt * 16 + quad * 4 + r] = fmaxf(acc[mt][nt][r], 0.f);
    }
    __syncthreads();
    float* out = (float*)outp;
    for (int fi = t; fi < 2048; fi += 256) {
      int co = fi >> 4, q4 = fi & 15;
      float4 v = *(float4*)&Yf[co * 68 + q4 * 4];
      *(float4*)&out[(size_t)(b * 128 + co) * HWPIX + y0 * 320 + x0 + q4 * 4] = v;
    }
  } else {
    short* Ybf = (short*)ldsraw;  // [64 px][136 co]
#pragma unroll
    for (int nt = 0; nt < 4; ++nt) {
      int col = cbase + nt * 16 + l15;
#pragma unroll
      for (int mt = 0; mt < 2; ++mt)
#pragma unroll
        for (int r = 0; r < 4; ++r)
          Ybf[(rbase + mt * 16 + quad * 4 + r) * 136 + col] =
              (short)f2bf(fmaxf(acc[mt][nt][r], 0.f));
    }
    __syncthreads();
    unsigned short* out = (unsigned short*)outp;
    for (int fi = t; fi < 1024; fi += 256) {
      int row = fi >> 4, c8 = fi & 15;
      ((uint4*)out)[((size_t)b * PCELLS + (size_t)(y0 + 1) * PW + x0 + 1 + row) * 16 + c8] =
          ((const uint4*)&Ybf[row * 136])[c8];
    }
  }
}

// ============================================================================
extern "C" void kernel_launch(void* const* d_in, const int* in_sizes, int n_in,
                              void* d_out, int out_size, void* d_ws, size_t ws_size,
                              hipStream_t stream) {
  const float* voxel_feats = (const float*)d_in[0];
  const float* pos0 = (const float*)d_in[1];
  const float* pos1 = (const float*)d_in[2];
  const float* ipw = (const float*)d_in[3];
  const float* ipb = (const float*)d_in[4];
  const float* opw = (const float*)d_in[5];
  const float* opb = (const float*)d_in[6];
  const float* l1w = (const float*)d_in[7];
  const float* l1b = (const float*)d_in[8];
  const float* l2w = (const float*)d_in[9];
  const float* l2b = (const float*)d_in[10];
  const float* n1w = (const float*)d_in[11];
  const float* n1b = (const float*)d_in[12];
  const float* n2w = (const float*)d_in[13];
  const float* n2b = (const float*)d_in[14];
  const float* convw = (const float*)d_in[15];
  const int* coors = (const int*)d_in[16];
  const int* ind0 = (const int*)d_in[17];
  const int* ind1 = (const int*)d_in[18];

  unsigned short* ws = (unsigned short*)d_ws;
  const size_t NC = (size_t)NVOX * CDIM;  // 15,360,000
  unsigned short* bx = ws;
  unsigned short* bq = ws + NC;
  unsigned short* bk = ws + 2 * NC;
  unsigned short* bv = ws + 3 * NC;
  unsigned short* bh = ws + 4 * NC;
  unsigned short* bff = ws + 5 * NC;       // 2*NC
  unsigned short* wB = ws + 7 * NC;        // 819200 bf16 weights
  unsigned short* ipwB = wB;               // 196608
  unsigned short* opwB = wB + 196608;      // 65536
  unsigned short* l1wB = wB + 262144;      // 131072
  unsigned short* l2wB = wB + 393216;      // 131072
  unsigned short* convB = wB + 524288;     // 294912
  int* idxmap = (int*)(wB + 819200);       // 204800 ints
  unsigned short* canvas = bq;             // padded: 26.54M shorts <= 2*NC (bq..bk)
  unsigned short* c1out = bv;              // padded: 26.54M shorts <= 2*NC (bv..bh)

  cvt_kernel<<<15000, 256, 0, stream>>>(voxel_feats, bx, 3840000);
  cvt_kernel<<<192, 256, 0, stream>>>(ipw, ipwB, 49152);
  cvt_kernel<<<64, 256, 0, stream>>>(opw, opwB, 16384);
  cvt_kernel<<<128, 256, 0, stream>>>(l1w, l1wB, 32768);
  cvt_kernel<<<128, 256, 0, stream>>>(l2w, l2wB, 32768);
  cvtT_kernel<<<1152, 256, 0, stream>>>(convw, convB);

  for (int l = 0; l < 4; ++l) {
    const int* ind = (l & 1) ? ind1 : ind0;
    const float* pos = (l & 1) ? pos1 : pos0;
    qkv_kernel<<<dim3(1875, 3), 256, 0, stream>>>(
        bx, pos, ind, ipwB + (size_t)l * 49152, ipb + l * 384, bq, bk, bv);
    attn_kernel<<<NWIN, 256, 0, stream>>>(bq, bk, bv);
    outln_kernel<<<1875, 256, 0, stream>>>(
        bq, ind, opwB + (size_t)l * 16384, opb + l * 128, bx,
        n1w + l * 128, n1b + l * 128, bh);
    ffn1_kernel<<<dim3(1875, 2), 256, 0, stream>>>(
        bh, l1wB + (size_t)l * 32768, l1b + l * 256, bff);
    ffn2_kernel<<<1875, 256, 0, stream>>>(
        bff, l2wB + (size_t)l * 32768, l2b + l * 128, bh,
        n2w + l * 128, n2b + l * 128, bx);
  }

  idx_init_kernel<<<800, 256, 0, stream>>>(idxmap);
  scatter_kernel<<<(NVOX + 255) / 256, 256, 0, stream>>>(coors, idxmap);
  canvas_kernel<<<(2 * PCELLS * 16 + 255) / 256, 256, 0, stream>>>(bx, idxmap, canvas);
  border_kernel<<<(2 * 1284 * 16 + 255) / 256, 256, 0, stream>>>(c1out);

  conv_kernel<0><<<dim3(5, 320, 2), 256, 0, stream>>>(canvas, convB, (void*)c1out);
  conv_kernel<1><<<dim3(5, 320, 2), 256, 0, stream>>>(c1out, convB + 9 * 16384, d_out);
}

// Round 3
// 1945.257 us; speedup vs baseline: 1.0017x; 1.0017x over previous
//
#include <hip/hip_runtime.h>
#include <math.h>

#define NVOX 120000
#define CDIM 128
#define NWIN 5000
#define HWPIX 102400
// padded canvas: 322 x 322 cells per batch
#define PW 322
#define PCELLS 103684

typedef __attribute__((ext_vector_type(8))) short short8;
typedef __attribute__((ext_vector_type(4))) float f32x4;

__device__ __forceinline__ unsigned short f2bf(float f) {
  unsigned u = __float_as_uint(f);
  return (unsigned short)((u + 0x7FFFu + ((u >> 16) & 1u)) >> 16);
}
__device__ __forceinline__ unsigned pack2(float a, float b) {
  return (unsigned)f2bf(a) | ((unsigned)f2bf(b) << 16);
}
__device__ __forceinline__ void unpack2(unsigned u, float& a, float& b) {
  a = __uint_as_float(u << 16);
  b = __uint_as_float(u & 0xFFFF0000u);
}

// ============================================================================
// MFMA core: block = 256 thr = 4 waves. Block tile M=64 x N=128, K staged 128.
// Wave wv: rows 32*(wv>>1)+{0..31} (2 m-tiles), cols 64*(wv&1)+{0..63} (4 n-tiles).
// LDS pitch 136 bf16 (272 B). A-frag: A[m=lane&15][k=quad*8+j];
// B-frag: W[n=lane&15][k=quad*8+j] (W is [N][K]). C/D: col=lane&15, row=quad*4+reg.
// ============================================================================
__device__ __forceinline__ void mma128(const short* __restrict__ As,
                                       const short* __restrict__ Ws,
                                       int aoff, int boff, f32x4 acc[2][4]) {
#pragma unroll
  for (int kc = 0; kc < 4; ++kc) {
    short8 a0 = *(const short8*)(As + aoff + kc * 32);
    short8 a1 = *(const short8*)(As + aoff + 136 * 16 + kc * 32);
#pragma unroll
    for (int nt = 0; nt < 4; ++nt) {
      short8 b = *(const short8*)(Ws + boff + nt * 136 * 16 + kc * 32);
      acc[0][nt] = __builtin_amdgcn_mfma_f32_16x16x32_bf16(a0, b, acc[0][nt], 0, 0, 0);
      acc[1][nt] = __builtin_amdgcn_mfma_f32_16x16x32_bf16(a1, b, acc[1][nt], 0, 0, 0);
    }
  }
}

// ---------------------------------------------------------------------------
__global__ __launch_bounds__(256) void cvt_kernel(const float* __restrict__ src,
                                                  unsigned short* __restrict__ dst, int n4) {
  int i = blockIdx.x * 256 + threadIdx.x;
  if (i >= n4) return;
  float4 v = ((const float4*)src)[i];
  uint2 o; o.x = pack2(v.x, v.y); o.y = pack2(v.z, v.w);
  ((uint2*)dst)[i] = o;
}

__global__ __launch_bounds__(256) void cvtT_kernel(const float* __restrict__ w,
                                                   unsigned short* __restrict__ wT) {
  int idx = blockIdx.x * 256 + threadIdx.x;
  if (idx >= 2 * 9 * 128 * 128) return;
  int ci = idx & 127;
  int co = (idx >> 7) & 127;
  int tap = (idx >> 14) % 9;
  int conv = idx / (9 * 16384);
  wT[idx] = f2bf(w[((size_t)(conv * 128 + co) * 128 + ci) * 9 + tap]);
}

// ---------------------------------------------------------------------------
__global__ __launch_bounds__(256) void qkv_kernel(
    const unsigned short* __restrict__ x, const float* __restrict__ pos,
    const int* __restrict__ ind, const unsigned short* __restrict__ ipwB,
    const float* __restrict__ ipb, unsigned short* __restrict__ qb,
    unsigned short* __restrict__ kb, unsigned short* __restrict__ vb) {
  __shared__ __align__(16) char ldsraw[52224];
  short* As = (short*)ldsraw;             // [64][136]
  short* Ws = (short*)(ldsraw + 17408);   // [128][136]
  const int t = threadIdx.x;
  const int lane = t & 63, wv = t >> 6;
  const int l15 = lane & 15, quad = lane >> 4;
  const int rbase = 32 * (wv >> 1), cbase = 64 * (wv & 1);
  const int mbase = blockIdx.x * 64;
  const int sec = blockIdx.y;
  f32x4 acc[2][4];
#pragma unroll
  for (int m = 0; m < 2; ++m)
#pragma unroll
    for (int n = 0; n < 4; ++n) acc[m][n] = (f32x4){0.f, 0.f, 0.f, 0.f};

  for (int fi = t; fi < 1024; fi += 256) {
    int row = fi >> 4, c8 = fi & 15;
    int vox = mbase + row;
    uint4 xv = ((const uint4*)x)[(size_t)vox * 16 + c8];
    if (sec < 2) {
      int s = ind[vox];
      const float4* pp = (const float4*)(pos + (size_t)s * 128 + c8 * 8);
      float4 p0 = pp[0], p1 = pp[1];
      float f0, f1, f2, f3, f4, f5, f6, f7;
      unpack2(xv.x, f0, f1); unpack2(xv.y, f2, f3);
      unpack2(xv.z, f4, f5); unpack2(xv.w, f6, f7);
      xv.x = pack2(f0 + p0.x, f1 + p0.y); xv.y = pack2(f2 + p0.z, f3 + p0.w);
      xv.z = pack2(f4 + p1.x, f5 + p1.y); xv.w = pack2(f6 + p1.z, f7 + p1.w);
    }
    *(uint4*)&As[row * 136 + c8 * 8] = xv;
  }
  for (int fi = t; fi < 2048; fi += 256) {
    int row = fi >> 4, c8 = fi & 15;
    ((uint4*)&Ws[row * 136])[c8] =
        ((const uint4*)(ipwB + (size_t)(sec * 128 + row) * 128))[c8];
  }
  __syncthreads();
  mma128(As, Ws, (rbase + l15) * 136 + quad * 8, (cbase + l15) * 136 + quad * 8, acc);
  __syncthreads();

  short* Ybf = (short*)ldsraw;  // [64][136]
#pragma unroll
  for (int nt = 0; nt < 4; ++nt) {
    int col = cbase + nt * 16 + l15;
    float bias = ipb[sec * 128 + col];
#pragma unroll
    for (int mt = 0; mt < 2; ++mt)
#pragma unroll
      for (int r = 0; r < 4; ++r)
        Ybf[(rbase + mt * 16 + quad * 4 + r) * 136 + col] =
            (short)f2bf(acc[mt][nt][r] + bias);
  }
  __syncthreads();
  unsigned short* dst = (sec == 0) ? qb : ((sec == 1) ? kb : vb);
  for (int fi = t; fi < 1024; fi += 256) {
    int row = fi >> 4, c8 = fi & 15;
    int s = ind[mbase + row];
    int slot = (s / 36) * 24 + (s % 36);
    ((uint4*)dst)[(size_t)slot * 16 + c8] = ((const uint4*)&Ybf[row * 136])[c8];
  }
}

// ---------------------------------------------------------------------------
__global__ __launch_bounds__(256) void attn_kernel(
    unsigned short* __restrict__ qb, const unsigned short* __restrict__ kb,
    const unsigned short* __restrict__ vb) {
  __shared__ float lds[14112];
  float* Qs = lds;          // [24][132]
  float* Ks = lds + 3168;
  float* Vs = lds + 6336;
  float* S = lds + 9504;    // [8][24][24]
  const int t = threadIdx.x;
  const size_t base = (size_t)blockIdx.x * 3072;
  for (int fi = t; fi < 1152; fi += 256) {
    int arr = fi / 384, rem = fi % 384;
    int row = rem >> 4, c8 = rem & 15;
    const unsigned short* src = arr == 0 ? qb : (arr == 1 ? kb : vb);
    uint4 raw = ((const uint4*)(src + base))[row * 16 + c8];
    float* dl = lds + arr * 3168 + row * 132 + c8 * 8;
    unpack2(raw.x, dl[0], dl[1]); unpack2(raw.y, dl[2], dl[3]);
    unpack2(raw.z, dl[4], dl[5]); unpack2(raw.w, dl[6], dl[7]);
  }
  __syncthreads();
  for (int idx = t; idx < 4608; idx += 256) {
    int hh = idx / 576, rem = idx % 576;
    int qq = rem / 24, kk = rem % 24;
    const float* qp = &Qs[qq * 132 + hh * 16];
    const float* kp = &Ks[kk * 132 + hh * 16];
    float s = 0.f;
#pragma unroll
    for (int d = 0; d < 16; ++d) s = fmaf(qp[d], kp[d], s);
    S[idx] = s * 0.25f;
  }
  __syncthreads();
  if (t < 192) {
    float* rowp = &S[t * 24];
    float m = rowp[0];
#pragma unroll
    for (int k2 = 1; k2 < 24; ++k2) m = fmaxf(m, rowp[k2]);
    float sum = 0.f;
#pragma unroll
    for (int k2 = 0; k2 < 24; ++k2) { float e = __expf(rowp[k2] - m); rowp[k2] = e; sum += e; }
    float inv = 1.f / sum;
#pragma unroll
    for (int k2 = 0; k2 < 24; ++k2) rowp[k2] *= inv;
  }
  __syncthreads();
  for (int idx = t; idx < 3072; idx += 256) {
    int hh = idx / 384, rem = idx % 384;
    int qq = rem >> 4, dd = rem & 15;
    const float* pp = &S[hh * 576 + qq * 24];
    const float* vp = &Vs[hh * 16 + dd];
    float o = 0.f;
#pragma unroll
    for (int k2 = 0; k2 < 24; ++k2) o = fmaf(pp[k2], vp[k2 * 132], o);
    qb[base + qq * 128 + hh * 16 + dd] = f2bf(o);
  }
}

// ---------------------------------------------------------------------------
__global__ __launch_bounds__(256) void outln_kernel(
    const unsigned short* __restrict__ o, const int* __restrict__ ind,
    const unsigned short* __restrict__ opwB, const float* __restrict__ opb,
    const unsigned short* __restrict__ xres, const float* __restrict__ lnw,
    const float* __restrict__ lnb, unsigned short* __restrict__ hout) {
  __shared__ __align__(16) char ldsraw[52224];
  short* As = (short*)ldsraw;
  short* Ws = (short*)(ldsraw + 17408);
  const int t = threadIdx.x;
  const int lane = t & 63, wv = t >> 6;
  const int l15 = lane & 15, quad = lane >> 4;
  const int rbase = 32 * (wv >> 1), cbase = 64 * (wv & 1);
  const int mbase = blockIdx.x * 64;
  f32x4 acc[2][4];
#pragma unroll
  for (int m = 0; m < 2; ++m)
#pragma unroll
    for (int n = 0; n < 4; ++n) acc[m][n] = (f32x4){0.f, 0.f, 0.f, 0.f};

  for (int fi = t; fi < 1024; fi += 256) {
    int row = fi >> 4, c8 = fi & 15;
    int s = ind[mbase + row];
    int slot = (s / 36) * 24 + (s % 36);
    *(uint4*)&As[row * 136 + c8 * 8] = ((const uint4*)o)[(size_t)slot * 16 + c8];
  }
  for (int fi = t; fi < 2048; fi += 256) {
    int row = fi >> 4, c8 = fi & 15;
    ((uint4*)&Ws[row * 136])[c8] = ((const uint4*)(opwB + (size_t)row * 128))[c8];
  }
  __syncthreads();
  mma128(As, Ws, (rbase + l15) * 136 + quad * 8, (cbase + l15) * 136 + quad * 8, acc);
  __syncthreads();

  float* Yf = (float*)ldsraw;               // [64][132]
  float* p1 = (float*)(ldsraw + 33792);
  float* p2 = (float*)(ldsraw + 34816);
  float* Ms = (float*)(ldsraw + 35840);
  float* Rs = (float*)(ldsraw + 36096);
#pragma unroll
  for (int nt = 0; nt < 4; ++nt) {
    int col = cbase + nt * 16 + l15;
    float bias = opb[col];
#pragma unroll
    for (int mt = 0; mt < 2; ++mt)
#pragma unroll
      for (int r = 0; r < 4; ++r)
        Yf[(rbase + mt * 16 + quad * 4 + r) * 132 + col] = acc[mt][nt][r] + bias;
  }
  __syncthreads();
  for (int fi = t; fi < 1024; fi += 256) {
    int row = fi >> 4, c8 = fi & 15;
    uint4 xv = ((const uint4*)xres)[(size_t)(mbase + row) * 16 + c8];
    float* yp = &Yf[row * 132 + c8 * 8];
    float a, b;
    unpack2(xv.x, a, b); yp[0] += a; yp[1] += b;
    unpack2(xv.y, a, b); yp[2] += a; yp[3] += b;
    unpack2(xv.z, a, b); yp[4] += a; yp[5] += b;
    unpack2(xv.w, a, b); yp[6] += a; yp[7] += b;
  }
  __syncthreads();
  {
    int r = t & 63, g = t >> 6;
    float s = 0.f, s2 = 0.f;
    for (int c = g * 32; c < g * 32 + 32; ++c) { float v = Yf[r * 132 + c]; s += v; s2 += v * v; }
    p1[g * 64 + r] = s; p2[g * 64 + r] = s2;
  }
  __syncthreads();
  if (t < 64) {
    float s = p1[t] + p1[64 + t] + p1[128 + t] + p1[192 + t];
    float s2 = p2[t] + p2[64 + t] + p2[128 + t] + p2[192 + t];
    float m = s * (1.f / 128.f);
    float var = s2 * (1.f / 128.f) - m * m;
    Ms[t] = m; Rs[t] = rsqrtf(var + 1e-5f);
  }
  __syncthreads();
  for (int fi = t; fi < 1024; fi += 256) {
    int row = fi >> 4, c8 = fi & 15;
    float m = Ms[row], rr = Rs[row];
    const float* yp = &Yf[row * 132 + c8 * 8];
    uint4 ov;
    float v0, v1;
#define LNPAIR(J, FLD) \
    v0 = (yp[2*J] - m) * rr * lnw[c8*8+2*J] + lnb[c8*8+2*J]; \
    v1 = (yp[2*J+1] - m) * rr * lnw[c8*8+2*J+1] + lnb[c8*8+2*J+1]; \
    ov.FLD = pack2(v0, v1);
    LNPAIR(0, x) LNPAIR(1, y) LNPAIR(2, z) LNPAIR(3, w)
#undef LNPAIR
    ((uint4*)hout)[(size_t)(mbase + row) * 16 + c8] = ov;
  }
}

// ---------------------------------------------------------------------------
__global__ __launch_bounds__(256) void ffn1_kernel(
    const unsigned short* __restrict__ h, const unsigned short* __restrict__ w1B,
    const float* __restrict__ b1, unsigned short* __restrict__ ff) {
  __shared__ __align__(16) char ldsraw[52224];
  short* As = (short*)ldsraw;
  short* Ws = (short*)(ldsraw + 17408);
  const int t = threadIdx.x;
  const int lane = t & 63, wv = t >> 6;
  const int l15 = lane & 15, quad = lane >> 4;
  const int rbase = 32 * (wv >> 1), cbase = 64 * (wv & 1);
  const int mbase = blockIdx.x * 64;
  const int by = blockIdx.y;
  f32x4 acc[2][4];
#pragma unroll
  for (int m = 0; m < 2; ++m)
#pragma unroll
    for (int n = 0; n < 4; ++n) acc[m][n] = (f32x4){0.f, 0.f, 0.f, 0.f};

  for (int fi = t; fi < 1024; fi += 256) {
    int row = fi >> 4, c8 = fi & 15;
    *(uint4*)&As[row * 136 + c8 * 8] = ((const uint4*)h)[(size_t)(mbase + row) * 16 + c8];
  }
  for (int fi = t; fi < 2048; fi += 256) {
    int row = fi >> 4, c8 = fi & 15;
    ((uint4*)&Ws[row * 136])[c8] =
        ((const uint4*)(w1B + (size_t)(by * 128 + row) * 128))[c8];
  }
  __syncthreads();
  mma128(As, Ws, (rbase + l15) * 136 + quad * 8, (cbase + l15) * 136 + quad * 8, acc);
  __syncthreads();

  short* Ybf = (short*)ldsraw;
#pragma unroll
  for (int nt = 0; nt < 4; ++nt) {
    int col = cbase + nt * 16 + l15;
    float bias = b1[by * 128 + col];
#pragma unroll
    for (int mt = 0; mt < 2; ++mt)
#pragma unroll
      for (int r = 0; r < 4; ++r) {
        float v = acc[mt][nt][r] + bias;
        float g = 0.5f * v * (1.f + erff(v * 0.70710678f));
        Ybf[(rbase + mt * 16 + quad * 4 + r) * 136 + col] = (short)f2bf(g);
      }
  }
  __syncthreads();
  for (int fi = t; fi < 1024; fi += 256) {
    int row = fi >> 4, c8 = fi & 15;
    ((uint4*)ff)[(size_t)(mbase + row) * 32 + by * 16 + c8] =
        ((const uint4*)&Ybf[row * 136])[c8];
  }
}

// ---------------------------------------------------------------------------
__global__ __launch_bounds__(256) void ffn2_kernel(
    const unsigned short* __restrict__ ff, const unsigned short* __restrict__ w2B,
    const float* __restrict__ b2, const unsigned short* __restrict__ hres,
    const float* __restrict__ lnw, const float* __restrict__ lnb,
    unsigned short* __restrict__ xout) {
  __shared__ __align__(16) char ldsraw[52224];
  short* As = (short*)ldsraw;
  short* Ws = (short*)(ldsraw + 17408);
  const int t = threadIdx.x;
  const int lane = t & 63, wv = t >> 6;
  const int l15 = lane & 15, quad = lane >> 4;
  const int rbase = 32 * (wv >> 1), cbase = 64 * (wv & 1);
  const int mbase = blockIdx.x * 64;
  f32x4 acc[2][4];
#pragma unroll
  for (int m = 0; m < 2; ++m)
#pragma unroll
    for (int n = 0; n < 4; ++n) acc[m][n] = (f32x4){0.f, 0.f, 0.f, 0.f};

  for (int k2 = 0; k2 < 2; ++k2) {
    if (k2) __syncthreads();
    for (int fi = t; fi < 1024; fi += 256) {
      int row = fi >> 4, c8 = fi & 15;
      *(uint4*)&As[row * 136 + c8 * 8] =
          ((const uint4*)ff)[(size_t)(mbase + row) * 32 + k2 * 16 + c8];
    }
    for (int fi = t; fi < 2048; fi += 256) {
      int row = fi >> 4, c8 = fi & 15;
      ((uint4*)&Ws[row * 136])[c8] =
          ((const uint4*)(w2B + (size_t)row * 256 + k2 * 128))[c8];
    }
    __syncthreads();
    mma128(As, Ws, (rbase + l15) * 136 + quad * 8, (cbase + l15) * 136 + quad * 8, acc);
  }
  __syncthreads();

  float* Yf = (float*)ldsraw;
  float* p1 = (float*)(ldsraw + 33792);
  float* p2 = (float*)(ldsraw + 34816);
  float* Ms = (float*)(ldsraw + 35840);
  float* Rs = (float*)(ldsraw + 36096);
#pragma unroll
  for (int nt = 0; nt < 4; ++nt) {
    int col = cbase + nt * 16 + l15;
    float bias = b2[col];
#pragma unroll
    for (int mt = 0; mt < 2; ++mt)
#pragma unroll
      for (int r = 0; r < 4; ++r)
        Yf[(rbase + mt * 16 + quad * 4 + r) * 132 + col] = acc[mt][nt][r] + bias;
  }
  __syncthreads();
  for (int fi = t; fi < 1024; fi += 256) {
    int row = fi >> 4, c8 = fi & 15;
    uint4 xv = ((const uint4*)hres)[(size_t)(mbase + row) * 16 + c8];
    float* yp = &Yf[row * 132 + c8 * 8];
    float a, b;
    unpack2(xv.x, a, b); yp[0] += a; yp[1] += b;
    unpack2(xv.y, a, b); yp[2] += a; yp[3] += b;
    unpack2(xv.z, a, b); yp[4] += a; yp[5] += b;
    unpack2(xv.w, a, b); yp[6] += a; yp[7] += b;
  }
  __syncthreads();
  {
    int r = t & 63, g = t >> 6;
    float s = 0.f, s2 = 0.f;
    for (int c = g * 32; c < g * 32 + 32; ++c) { float v = Yf[r * 132 + c]; s += v; s2 += v * v; }
    p1[g * 64 + r] = s; p2[g * 64 + r] = s2;
  }
  __syncthreads();
  if (t < 64) {
    float s = p1[t] + p1[64 + t] + p1[128 + t] + p1[192 + t];
    float s2 = p2[t] + p2[64 + t] + p2[128 + t] + p2[192 + t];
    float m = s * (1.f / 128.f);
    float var = s2 * (1.f / 128.f) - m * m;
    Ms[t] = m; Rs[t] = rsqrtf(var + 1e-5f);
  }
  __syncthreads();
  for (int fi = t; fi < 1024; fi += 256) {
    int row = fi >> 4, c8 = fi & 15;
    float m = Ms[row], rr = Rs[row];
    const float* yp = &Yf[row * 132 + c8 * 8];
    uint4 ov;
    float v0, v1;
#define LNPAIR(J, FLD) \
    v0 = (yp[2*J] - m) * rr * lnw[c8*8+2*J] + lnb[c8*8+2*J]; \
    v1 = (yp[2*J+1] - m) * rr * lnw[c8*8+2*J+1] + lnb[c8*8+2*J+1]; \
    ov.FLD = pack2(v0, v1);
    LNPAIR(0, x) LNPAIR(1, y) LNPAIR(2, z) LNPAIR(3, w)
#undef LNPAIR
    ((uint4*)xout)[(size_t)(mbase + row) * 16 + c8] = ov;
  }
}

// ---------------------------------------------------------------------------
__global__ void idx_init_kernel(int* __restrict__ idxmap) {
  int i = blockIdx.x * 256 + threadIdx.x;
  if (i < 2 * HWPIX) idxmap[i] = -1;
}

__global__ void scatter_kernel(const int* __restrict__ coors, int* __restrict__ idxmap) {
  int i = blockIdx.x * 256 + threadIdx.x;
  if (i >= NVOX) return;
  int b = coors[i * 4 + 0], y = coors[i * 4 + 2], xx = coors[i * 4 + 3];
  atomicMax(&idxmap[b * HWPIX + y * 320 + xx], i);
}

// writes PADDED canvas [b][322][322][128]; halo cells = 0
__global__ void canvas_kernel(const unsigned short* __restrict__ x,
                              const int* __restrict__ idxmap,
                              unsigned short* __restrict__ canvas) {
  int idx = blockIdx.x * 256 + threadIdx.x;
  if (idx >= 2 * PCELLS * 16) return;
  int cell = idx >> 4, c8 = idx & 15;
  int b = (cell >= PCELLS) ? 1 : 0;
  cell -= b * PCELLS;
  int yy = cell / PW, xx = cell - yy * PW;
  uint4 v = {0u, 0u, 0u, 0u};
  if (yy >= 1 && yy <= 320 && xx >= 1 && xx <= 320) {
    int vox = idxmap[b * HWPIX + (yy - 1) * 320 + (xx - 1)];
    if (vox >= 0) v = ((const uint4*)x)[(size_t)vox * 16 + c8];
  }
  ((uint4*)canvas)[idx] = v;
}

// zero the halo cells of a padded NHWC buffer (for c1out between the convs)
__global__ void border_kernel(unsigned short* __restrict__ buf) {
  int i = blockIdx.x * 256 + threadIdx.x;
  if (i >= 2 * 1284 * 16) return;
  int c8 = i & 15, j = i >> 4;
  int b = (j >= 1284) ? 1 : 0;
  j -= b * 1284;
  int cell;
  if (j < 322) cell = j;                                   // top row
  else if (j < 644) cell = 321 * PW + (j - 322);           // bottom row
  else { int j2 = j - 644; cell = (1 + (j2 >> 1)) * PW + (j2 & 1) * 321; }  // sides
  uint4 z = {0u, 0u, 0u, 0u};
  ((uint4*)buf)[((size_t)b * PCELLS + cell) * 16 + c8] = z;
}

// ---------------------------------------------------------------------------
// Conv 3x3, padded NHWC bf16 input [b][322][322][128].
// Round-0 structure (M=64 px x N=128 co, patch+weights in LDS, 52.8 KB,
// 3 blocks/CU) + T14 issue-early/write-late staging: next tap's weights and
// next dy's patch row are global-loaded into registers BEFORE the current
// tap's 32 MFMAs, ds-written after the post-MFMA barrier.
// __launch_bounds__(256, 3): LDS caps us at 3 blocks/CU = 3 waves/EU anyway;
// this raises the VGPR budget to ~170 so the ~120 live VGPRs (acc 32 + wreg 32
// + patch prefetch 20 + frags/addr) do NOT spill to scratch. (Round-2 lesson:
// default allocation chose 72 VGPRs and spilled ~940 MB to HBM.)
template <int NCHW_OUT>
__global__ __launch_bounds__(256, 3) void conv_kernel(
    const unsigned short* __restrict__ in, const unsigned short* __restrict__ wTb,
    void* __restrict__ outp) {
  __shared__ __align__(16) char ldsraw[52768];
  short* patch = (short*)ldsraw;           // [66 cols][136]
  short* Wt = (short*)(ldsraw + 17952);    // [128 co][136]
  const int t = threadIdx.x;
  const int lane = t & 63, wv = t >> 6;
  const int l15 = lane & 15, quad = lane >> 4;
  const int rbase = 32 * (wv >> 1), cbase = 64 * (wv & 1);
  const int x0 = blockIdx.x * 64;
  const int y0 = blockIdx.y;               // output row, padded row = y0+1
  const int b = blockIdx.z;
  const unsigned short* inb = in + (size_t)b * PCELLS * 128;
  const int srow = t >> 4, sc8 = t & 15;   // weight staging coords

  f32x4 acc[2][4];
#pragma unroll
  for (int m = 0; m < 2; ++m)
#pragma unroll
    for (int n = 0; n < 4; ++n) acc[m][n] = (f32x4){0.f, 0.f, 0.f, 0.f};

  uint4 wreg[8];
  uint4 pp[4], px4;

  // --- prologue: load patch(dy=0) + weights(tap=0), write, one barrier ---
  {
    const uint4* src = (const uint4*)inb + ((size_t)y0 * PW + x0) * 16;
#pragma unroll
    for (int k = 0; k < 4; ++k) pp[k] = src[t + 256 * k];
    if (t < 32) px4 = src[1024 + t];
  }
#pragma unroll
  for (int i = 0; i < 8; ++i)
    wreg[i] = ((const uint4*)(wTb + (size_t)(i * 16 + srow) * 128))[sc8];
#pragma unroll
  for (int k = 0; k < 4; ++k) {
    int e = t + 256 * k;
    *(uint4*)&patch[(e >> 4) * 136 + (e & 15) * 8] = pp[k];
  }
  if (t < 32) { int e = 1024 + t; *(uint4*)&patch[(e >> 4) * 136 + (e & 15) * 8] = px4; }
#pragma unroll
  for (int i = 0; i < 8; ++i)
    *(uint4*)&Wt[(i * 16 + srow) * 136 + sc8 * 8] = wreg[i];
  __syncthreads();

#pragma unroll
  for (int tap = 0; tap < 9; ++tap) {
    const int dy = tap / 3, dx = tap % 3;
    const bool pfP = (dx == 2) && (dy < 2);   // prefetch patch for dy+1
    const bool pfW = (tap < 8);               // prefetch weights for tap+1
    if (pfP) {
      const uint4* src = (const uint4*)inb + ((size_t)(y0 + dy + 1) * PW + x0) * 16;
#pragma unroll
      for (int k = 0; k < 4; ++k) pp[k] = src[t + 256 * k];
      if (t < 32) px4 = src[1024 + t];
    }
    if (pfW) {
#pragma unroll
      for (int i = 0; i < 8; ++i)
        wreg[i] = ((const uint4*)(wTb + (size_t)((tap + 1) * 128 + i * 16 + srow) * 128))[sc8];
    }
    mma128(patch, Wt, (rbase + l15 + dx) * 136 + quad * 8,
           (cbase + l15) * 136 + quad * 8, acc);
    __syncthreads();   // all waves done reading current LDS contents
    if (pfW) {
      if (pfP) {
#pragma unroll
        for (int k = 0; k < 4; ++k) {
          int e = t + 256 * k;
          *(uint4*)&patch[(e >> 4) * 136 + (e & 15) * 8] = pp[k];
        }
        if (t < 32) { int e = 1024 + t; *(uint4*)&patch[(e >> 4) * 136 + (e & 15) * 8] = px4; }
      }
#pragma unroll
      for (int i = 0; i < 8; ++i)
        *(uint4*)&Wt[(i * 16 + srow) * 136 + sc8 * 8] = wreg[i];
      __syncthreads();
    }
  }
  // last loop iteration ends with a barrier (post-MFMA) -> LDS reuse safe

  if (NCHW_OUT) {
    float* Yf = (float*)ldsraw;  // [128 co][68 px]
#pragma unroll
    for (int nt = 0; nt < 4; ++nt) {
      int col = cbase + nt * 16 + l15;
#pragma unroll
      for (int mt = 0; mt < 2; ++mt)
#pragma unroll
        for (int r = 0; r < 4; ++r)
          Yf[col * 68 + rbase + mt * 16 + quad * 4 + r] = fmaxf(acc[mt][nt][r], 0.f);
    }
    __syncthreads();
    float* out = (float*)outp;
    for (int fi = t; fi < 2048; fi += 256) {
      int co = fi >> 4, q4 = fi & 15;
      float4 v = *(float4*)&Yf[co * 68 + q4 * 4];
      *(float4*)&out[(size_t)(b * 128 + co) * HWPIX + y0 * 320 + x0 + q4 * 4] = v;
    }
  } else {
    short* Ybf = (short*)ldsraw;  // [64 px][136 co]
#pragma unroll
    for (int nt = 0; nt < 4; ++nt) {
      int col = cbase + nt * 16 + l15;
#pragma unroll
      for (int mt = 0; mt < 2; ++mt)
#pragma unroll
        for (int r = 0; r < 4; ++r)
          Ybf[(rbase + mt * 16 + quad * 4 + r) * 136 + col] =
              (short)f2bf(fmaxf(acc[mt][nt][r], 0.f));
    }
    __syncthreads();
    unsigned short* out = (unsigned short*)outp;
    for (int fi = t; fi < 1024; fi += 256) {
      int row = fi >> 4, c8 = fi & 15;
      ((uint4*)out)[((size_t)b * PCELLS + (size_t)(y0 + 1) * PW + x0 + 1 + row) * 16 + c8] =
          ((const uint4*)&Ybf[row * 136])[c8];
    }
  }
}

// ============================================================================
extern "C" void kernel_launch(void* const* d_in, const int* in_sizes, int n_in,
                              void* d_out, int out_size, void* d_ws, size_t ws_size,
                              hipStream_t stream) {
  const float* voxel_feats = (const float*)d_in[0];
  const float* pos0 = (const float*)d_in[1];
  const float* pos1 = (const float*)d_in[2];
  const float* ipw = (const float*)d_in[3];
  const float* ipb = (const float*)d_in[4];
  const float* opw = (const float*)d_in[5];
  const float* opb = (const float*)d_in[6];
  const float* l1w = (const float*)d_in[7];
  const float* l1b = (const float*)d_in[8];
  const float* l2w = (const float*)d_in[9];
  const float* l2b = (const float*)d_in[10];
  const float* n1w = (const float*)d_in[11];
  const float* n1b = (const float*)d_in[12];
  const float* n2w = (const float*)d_in[13];
  const float* n2b = (const float*)d_in[14];
  const float* convw = (const float*)d_in[15];
  const int* coors = (const int*)d_in[16];
  const int* ind0 = (const int*)d_in[17];
  const int* ind1 = (const int*)d_in[18];

  unsigned short* ws = (unsigned short*)d_ws;
  const size_t NC = (size_t)NVOX * CDIM;  // 15,360,000
  unsigned short* bx = ws;
  unsigned short* bq = ws + NC;
  unsigned short* bk = ws + 2 * NC;
  unsigned short* bv = ws + 3 * NC;
  unsigned short* bh = ws + 4 * NC;
  unsigned short* bff = ws + 5 * NC;       // 2*NC
  unsigned short* wB = ws + 7 * NC;        // 819200 bf16 weights
  unsigned short* ipwB = wB;               // 196608
  unsigned short* opwB = wB + 196608;      // 65536
  unsigned short* l1wB = wB + 262144;      // 131072
  unsigned short* l2wB = wB + 393216;      // 131072
  unsigned short* convB = wB + 524288;     // 294912
  int* idxmap = (int*)(wB + 819200);       // 204800 ints
  unsigned short* canvas = bq;             // padded: 26.54M shorts <= 2*NC (bq..bk)
  unsigned short* c1out = bv;              // padded: 26.54M shorts <= 2*NC (bv..bh)

  cvt_kernel<<<15000, 256, 0, stream>>>(voxel_feats, bx, 3840000);
  cvt_kernel<<<192, 256, 0, stream>>>(ipw, ipwB, 49152);
  cvt_kernel<<<64, 256, 0, stream>>>(opw, opwB, 16384);
  cvt_kernel<<<128, 256, 0, stream>>>(l1w, l1wB, 32768);
  cvt_kernel<<<128, 256, 0, stream>>>(l2w, l2wB, 32768);
  cvtT_kernel<<<1152, 256, 0, stream>>>(convw, convB);

  for (int l = 0; l < 4; ++l) {
    const int* ind = (l & 1) ? ind1 : ind0;
    const float* pos = (l & 1) ? pos1 : pos0;
    qkv_kernel<<<dim3(1875, 3), 256, 0, stream>>>(
        bx, pos, ind, ipwB + (size_t)l * 49152, ipb + l * 384, bq, bk, bv);
    attn_kernel<<<NWIN, 256, 0, stream>>>(bq, bk, bv);
    outln_kernel<<<1875, 256, 0, stream>>>(
        bq, ind, opwB + (size_t)l * 16384, opb + l * 128, bx,
        n1w + l * 128, n1b + l * 128, bh);
    ffn1_kernel<<<dim3(1875, 2), 256, 0, stream>>>(
        bh, l1wB + (size_t)l * 32768, l1b + l * 256, bff);
    ffn2_kernel<<<1875, 256, 0, stream>>>(
        bff, l2wB + (size_t)l * 32768, l2b + l * 128, bh,
        n2w + l * 128, n2b + l * 128, bx);
  }

  idx_init_kernel<<<800, 256, 0, stream>>>(idxmap);
  scatter_kernel<<<(NVOX + 255) / 256, 256, 0, stream>>>(coors, idxmap);
  canvas_kernel<<<(2 * PCELLS * 16 + 255) / 256, 256, 0, stream>>>(bx, idxmap, canvas);
  border_kernel<<<(2 * 1284 * 16 + 255) / 256, 256, 0, stream>>>(c1out);

  conv_kernel<0><<<dim3(5, 320, 2), 256, 0, stream>>>(canvas, convB, (void*)c1out);
  conv_kernel<1><<<dim3(5, 320, 2), 256, 0, stream>>>(c1out, convB + 9 * 16384, d_out);
}

// Round 4
// 1944.409 us; speedup vs baseline: 1.0022x; 1.0004x over previous
//
#include <hip/hip_runtime.h>
#include <math.h>

#define NVOX 120000
#define CDIM 128
#define NWIN 5000
#define HWPIX 102400
// padded canvas: 322 x 322 cells per batch
#define PW 322
#define PCELLS 103684

typedef __attribute__((ext_vector_type(8))) short short8;
typedef __attribute__((ext_vector_type(4))) float f32x4;

__device__ __forceinline__ unsigned short f2bf(float f) {
  unsigned u = __float_as_uint(f);
  return (unsigned short)((u + 0x7FFFu + ((u >> 16) & 1u)) >> 16);
}
__device__ __forceinline__ unsigned pack2(float a, float b) {
  return (unsigned)f2bf(a) | ((unsigned)f2bf(b) << 16);
}
__device__ __forceinline__ void unpack2(unsigned u, float& a, float& b) {
  a = __uint_as_float(u << 16);
  b = __uint_as_float(u & 0xFFFF0000u);
}

// ============================================================================
// MFMA core: block = 256 thr = 4 waves. Block tile M=64 x N=128, K staged 128.
// Wave wv: rows 32*(wv>>1)+{0..31} (2 m-tiles), cols 64*(wv&1)+{0..63} (4 n-tiles).
// LDS pitch 136 bf16 (272 B). A-frag: A[m=lane&15][k=quad*8+j];
// B-frag: W[n=lane&15][k=quad*8+j] (W is [N][K]). C/D: col=lane&15, row=quad*4+reg.
// ============================================================================
__device__ __forceinline__ void mma128(const short* __restrict__ As,
                                       const short* __restrict__ Ws,
                                       int aoff, int boff, f32x4 acc[2][4]) {
#pragma unroll
  for (int kc = 0; kc < 4; ++kc) {
    short8 a0 = *(const short8*)(As + aoff + kc * 32);
    short8 a1 = *(const short8*)(As + aoff + 136 * 16 + kc * 32);
#pragma unroll
    for (int nt = 0; nt < 4; ++nt) {
      short8 b = *(const short8*)(Ws + boff + nt * 136 * 16 + kc * 32);
      acc[0][nt] = __builtin_amdgcn_mfma_f32_16x16x32_bf16(a0, b, acc[0][nt], 0, 0, 0);
      acc[1][nt] = __builtin_amdgcn_mfma_f32_16x16x32_bf16(a1, b, acc[1][nt], 0, 0, 0);
    }
  }
}

// ---------------------------------------------------------------------------
__global__ __launch_bounds__(256) void cvt_kernel(const float* __restrict__ src,
                                                  unsigned short* __restrict__ dst, int n4) {
  int i = blockIdx.x * 256 + threadIdx.x;
  if (i >= n4) return;
  float4 v = ((const float4*)src)[i];
  uint2 o; o.x = pack2(v.x, v.y); o.y = pack2(v.z, v.w);
  ((uint2*)dst)[i] = o;
}

__global__ __launch_bounds__(256) void cvtT_kernel(const float* __restrict__ w,
                                                   unsigned short* __restrict__ wT) {
  int idx = blockIdx.x * 256 + threadIdx.x;
  if (idx >= 2 * 9 * 128 * 128) return;
  int ci = idx & 127;
  int co = (idx >> 7) & 127;
  int tap = (idx >> 14) % 9;
  int conv = idx / (9 * 16384);
  wT[idx] = f2bf(w[((size_t)(conv * 128 + co) * 128 + ci) * 9 + tap]);
}

// ---------------------------------------------------------------------------
__global__ __launch_bounds__(256) void qkv_kernel(
    const unsigned short* __restrict__ x, const float* __restrict__ pos,
    const int* __restrict__ ind, const unsigned short* __restrict__ ipwB,
    const float* __restrict__ ipb, unsigned short* __restrict__ qb,
    unsigned short* __restrict__ kb, unsigned short* __restrict__ vb) {
  __shared__ __align__(16) char ldsraw[52224];
  short* As = (short*)ldsraw;             // [64][136]
  short* Ws = (short*)(ldsraw + 17408);   // [128][136]
  const int t = threadIdx.x;
  const int lane = t & 63, wv = t >> 6;
  const int l15 = lane & 15, quad = lane >> 4;
  const int rbase = 32 * (wv >> 1), cbase = 64 * (wv & 1);
  const int mbase = blockIdx.x * 64;
  const int sec = blockIdx.y;
  f32x4 acc[2][4];
#pragma unroll
  for (int m = 0; m < 2; ++m)
#pragma unroll
    for (int n = 0; n < 4; ++n) acc[m][n] = (f32x4){0.f, 0.f, 0.f, 0.f};

  for (int fi = t; fi < 1024; fi += 256) {
    int row = fi >> 4, c8 = fi & 15;
    int vox = mbase + row;
    uint4 xv = ((const uint4*)x)[(size_t)vox * 16 + c8];
    if (sec < 2) {
      int s = ind[vox];
      const float4* pp = (const float4*)(pos + (size_t)s * 128 + c8 * 8);
      float4 p0 = pp[0], p1 = pp[1];
      float f0, f1, f2, f3, f4, f5, f6, f7;
      unpack2(xv.x, f0, f1); unpack2(xv.y, f2, f3);
      unpack2(xv.z, f4, f5); unpack2(xv.w, f6, f7);
      xv.x = pack2(f0 + p0.x, f1 + p0.y); xv.y = pack2(f2 + p0.z, f3 + p0.w);
      xv.z = pack2(f4 + p1.x, f5 + p1.y); xv.w = pack2(f6 + p1.z, f7 + p1.w);
    }
    *(uint4*)&As[row * 136 + c8 * 8] = xv;
  }
  for (int fi = t; fi < 2048; fi += 256) {
    int row = fi >> 4, c8 = fi & 15;
    ((uint4*)&Ws[row * 136])[c8] =
        ((const uint4*)(ipwB + (size_t)(sec * 128 + row) * 128))[c8];
  }
  __syncthreads();
  mma128(As, Ws, (rbase + l15) * 136 + quad * 8, (cbase + l15) * 136 + quad * 8, acc);
  __syncthreads();

  short* Ybf = (short*)ldsraw;  // [64][136]
#pragma unroll
  for (int nt = 0; nt < 4; ++nt) {
    int col = cbase + nt * 16 + l15;
    float bias = ipb[sec * 128 + col];
#pragma unroll
    for (int mt = 0; mt < 2; ++mt)
#pragma unroll
      for (int r = 0; r < 4; ++r)
        Ybf[(rbase + mt * 16 + quad * 4 + r) * 136 + col] =
            (short)f2bf(acc[mt][nt][r] + bias);
  }
  __syncthreads();
  unsigned short* dst = (sec == 0) ? qb : ((sec == 1) ? kb : vb);
  for (int fi = t; fi < 1024; fi += 256) {
    int row = fi >> 4, c8 = fi & 15;
    int s = ind[mbase + row];
    int slot = (s / 36) * 24 + (s % 36);
    ((uint4*)dst)[(size_t)slot * 16 + c8] = ((const uint4*)&Ybf[row * 136])[c8];
  }
}

// ---------------------------------------------------------------------------
__global__ __launch_bounds__(256) void attn_kernel(
    unsigned short* __restrict__ qb, const unsigned short* __restrict__ kb,
    const unsigned short* __restrict__ vb) {
  __shared__ float lds[14112];
  float* Qs = lds;          // [24][132]
  float* Ks = lds + 3168;
  float* Vs = lds + 6336;
  float* S = lds + 9504;    // [8][24][24]
  const int t = threadIdx.x;
  const size_t base = (size_t)blockIdx.x * 3072;
  for (int fi = t; fi < 1152; fi += 256) {
    int arr = fi / 384, rem = fi % 384;
    int row = rem >> 4, c8 = rem & 15;
    const unsigned short* src = arr == 0 ? qb : (arr == 1 ? kb : vb);
    uint4 raw = ((const uint4*)(src + base))[row * 16 + c8];
    float* dl = lds + arr * 3168 + row * 132 + c8 * 8;
    unpack2(raw.x, dl[0], dl[1]); unpack2(raw.y, dl[2], dl[3]);
    unpack2(raw.z, dl[4], dl[5]); unpack2(raw.w, dl[6], dl[7]);
  }
  __syncthreads();
  for (int idx = t; idx < 4608; idx += 256) {
    int hh = idx / 576, rem = idx % 576;
    int qq = rem / 24, kk = rem % 24;
    const float* qp = &Qs[qq * 132 + hh * 16];
    const float* kp = &Ks[kk * 132 + hh * 16];
    float s = 0.f;
#pragma unroll
    for (int d = 0; d < 16; ++d) s = fmaf(qp[d], kp[d], s);
    S[idx] = s * 0.25f;
  }
  __syncthreads();
  if (t < 192) {
    float* rowp = &S[t * 24];
    float m = rowp[0];
#pragma unroll
    for (int k2 = 1; k2 < 24; ++k2) m = fmaxf(m, rowp[k2]);
    float sum = 0.f;
#pragma unroll
    for (int k2 = 0; k2 < 24; ++k2) { float e = __expf(rowp[k2] - m); rowp[k2] = e; sum += e; }
    float inv = 1.f / sum;
#pragma unroll
    for (int k2 = 0; k2 < 24; ++k2) rowp[k2] *= inv;
  }
  __syncthreads();
  for (int idx = t; idx < 3072; idx += 256) {
    int hh = idx / 384, rem = idx % 384;
    int qq = rem >> 4, dd = rem & 15;
    const float* pp = &S[hh * 576 + qq * 24];
    const float* vp = &Vs[hh * 16 + dd];
    float o = 0.f;
#pragma unroll
    for (int k2 = 0; k2 < 24; ++k2) o = fmaf(pp[k2], vp[k2 * 132], o);
    qb[base + qq * 128 + hh * 16 + dd] = f2bf(o);
  }
}

// ---------------------------------------------------------------------------
__global__ __launch_bounds__(256) void outln_kernel(
    const unsigned short* __restrict__ o, const int* __restrict__ ind,
    const unsigned short* __restrict__ opwB, const float* __restrict__ opb,
    const unsigned short* __restrict__ xres, const float* __restrict__ lnw,
    const float* __restrict__ lnb, unsigned short* __restrict__ hout) {
  __shared__ __align__(16) char ldsraw[52224];
  short* As = (short*)ldsraw;
  short* Ws = (short*)(ldsraw + 17408);
  const int t = threadIdx.x;
  const int lane = t & 63, wv = t >> 6;
  const int l15 = lane & 15, quad = lane >> 4;
  const int rbase = 32 * (wv >> 1), cbase = 64 * (wv & 1);
  const int mbase = blockIdx.x * 64;
  f32x4 acc[2][4];
#pragma unroll
  for (int m = 0; m < 2; ++m)
#pragma unroll
    for (int n = 0; n < 4; ++n) acc[m][n] = (f32x4){0.f, 0.f, 0.f, 0.f};

  for (int fi = t; fi < 1024; fi += 256) {
    int row = fi >> 4, c8 = fi & 15;
    int s = ind[mbase + row];
    int slot = (s / 36) * 24 + (s % 36);
    *(uint4*)&As[row * 136 + c8 * 8] = ((const uint4*)o)[(size_t)slot * 16 + c8];
  }
  for (int fi = t; fi < 2048; fi += 256) {
    int row = fi >> 4, c8 = fi & 15;
    ((uint4*)&Ws[row * 136])[c8] = ((const uint4*)(opwB + (size_t)row * 128))[c8];
  }
  __syncthreads();
  mma128(As, Ws, (rbase + l15) * 136 + quad * 8, (cbase + l15) * 136 + quad * 8, acc);
  __syncthreads();

  float* Yf = (float*)ldsraw;               // [64][132]
  float* p1 = (float*)(ldsraw + 33792);
  float* p2 = (float*)(ldsraw + 34816);
  float* Ms = (float*)(ldsraw + 35840);
  float* Rs = (float*)(ldsraw + 36096);
#pragma unroll
  for (int nt = 0; nt < 4; ++nt) {
    int col = cbase + nt * 16 + l15;
    float bias = opb[col];
#pragma unroll
    for (int mt = 0; mt < 2; ++mt)
#pragma unroll
      for (int r = 0; r < 4; ++r)
        Yf[(rbase + mt * 16 + quad * 4 + r) * 132 + col] = acc[mt][nt][r] + bias;
  }
  __syncthreads();
  for (int fi = t; fi < 1024; fi += 256) {
    int row = fi >> 4, c8 = fi & 15;
    uint4 xv = ((const uint4*)xres)[(size_t)(mbase + row) * 16 + c8];
    float* yp = &Yf[row * 132 + c8 * 8];
    float a, b;
    unpack2(xv.x, a, b); yp[0] += a; yp[1] += b;
    unpack2(xv.y, a, b); yp[2] += a; yp[3] += b;
    unpack2(xv.z, a, b); yp[4] += a; yp[5] += b;
    unpack2(xv.w, a, b); yp[6] += a; yp[7] += b;
  }
  __syncthreads();
  {
    int r = t & 63, g = t >> 6;
    float s = 0.f, s2 = 0.f;
    for (int c = g * 32; c < g * 32 + 32; ++c) { float v = Yf[r * 132 + c]; s += v; s2 += v * v; }
    p1[g * 64 + r] = s; p2[g * 64 + r] = s2;
  }
  __syncthreads();
  if (t < 64) {
    float s = p1[t] + p1[64 + t] + p1[128 + t] + p1[192 + t];
    float s2 = p2[t] + p2[64 + t] + p2[128 + t] + p2[192 + t];
    float m = s * (1.f / 128.f);
    float var = s2 * (1.f / 128.f) - m * m;
    Ms[t] = m; Rs[t] = rsqrtf(var + 1e-5f);
  }
  __syncthreads();
  for (int fi = t; fi < 1024; fi += 256) {
    int row = fi >> 4, c8 = fi & 15;
    float m = Ms[row], rr = Rs[row];
    const float* yp = &Yf[row * 132 + c8 * 8];
    uint4 ov;
    float v0, v1;
#define LNPAIR(J, FLD) \
    v0 = (yp[2*J] - m) * rr * lnw[c8*8+2*J] + lnb[c8*8+2*J]; \
    v1 = (yp[2*J+1] - m) * rr * lnw[c8*8+2*J+1] + lnb[c8*8+2*J+1]; \
    ov.FLD = pack2(v0, v1);
    LNPAIR(0, x) LNPAIR(1, y) LNPAIR(2, z) LNPAIR(3, w)
#undef LNPAIR
    ((uint4*)hout)[(size_t)(mbase + row) * 16 + c8] = ov;
  }
}

// ---------------------------------------------------------------------------
__global__ __launch_bounds__(256) void ffn1_kernel(
    const unsigned short* __restrict__ h, const unsigned short* __restrict__ w1B,
    const float* __restrict__ b1, unsigned short* __restrict__ ff) {
  __shared__ __align__(16) char ldsraw[52224];
  short* As = (short*)ldsraw;
  short* Ws = (short*)(ldsraw + 17408);
  const int t = threadIdx.x;
  const int lane = t & 63, wv = t >> 6;
  const int l15 = lane & 15, quad = lane >> 4;
  const int rbase = 32 * (wv >> 1), cbase = 64 * (wv & 1);
  const int mbase = blockIdx.x * 64;
  const int by = blockIdx.y;
  f32x4 acc[2][4];
#pragma unroll
  for (int m = 0; m < 2; ++m)
#pragma unroll
    for (int n = 0; n < 4; ++n) acc[m][n] = (f32x4){0.f, 0.f, 0.f, 0.f};

  for (int fi = t; fi < 1024; fi += 256) {
    int row = fi >> 4, c8 = fi & 15;
    *(uint4*)&As[row * 136 + c8 * 8] = ((const uint4*)h)[(size_t)(mbase + row) * 16 + c8];
  }
  for (int fi = t; fi < 2048; fi += 256) {
    int row = fi >> 4, c8 = fi & 15;
    ((uint4*)&Ws[row * 136])[c8] =
        ((const uint4*)(w1B + (size_t)(by * 128 + row) * 128))[c8];
  }
  __syncthreads();
  mma128(As, Ws, (rbase + l15) * 136 + quad * 8, (cbase + l15) * 136 + quad * 8, acc);
  __syncthreads();

  short* Ybf = (short*)ldsraw;
#pragma unroll
  for (int nt = 0; nt < 4; ++nt) {
    int col = cbase + nt * 16 + l15;
    float bias = b1[by * 128 + col];
#pragma unroll
    for (int mt = 0; mt < 2; ++mt)
#pragma unroll
      for (int r = 0; r < 4; ++r) {
        float v = acc[mt][nt][r] + bias;
        float g = 0.5f * v * (1.f + erff(v * 0.70710678f));
        Ybf[(rbase + mt * 16 + quad * 4 + r) * 136 + col] = (short)f2bf(g);
      }
  }
  __syncthreads();
  for (int fi = t; fi < 1024; fi += 256) {
    int row = fi >> 4, c8 = fi & 15;
    ((uint4*)ff)[(size_t)(mbase + row) * 32 + by * 16 + c8] =
        ((const uint4*)&Ybf[row * 136])[c8];
  }
}

// ---------------------------------------------------------------------------
__global__ __launch_bounds__(256) void ffn2_kernel(
    const unsigned short* __restrict__ ff, const unsigned short* __restrict__ w2B,
    const float* __restrict__ b2, const unsigned short* __restrict__ hres,
    const float* __restrict__ lnw, const float* __restrict__ lnb,
    unsigned short* __restrict__ xout) {
  __shared__ __align__(16) char ldsraw[52224];
  short* As = (short*)ldsraw;
  short* Ws = (short*)(ldsraw + 17408);
  const int t = threadIdx.x;
  const int lane = t & 63, wv = t >> 6;
  const int l15 = lane & 15, quad = lane >> 4;
  const int rbase = 32 * (wv >> 1), cbase = 64 * (wv & 1);
  const int mbase = blockIdx.x * 64;
  f32x4 acc[2][4];
#pragma unroll
  for (int m = 0; m < 2; ++m)
#pragma unroll
    for (int n = 0; n < 4; ++n) acc[m][n] = (f32x4){0.f, 0.f, 0.f, 0.f};

  for (int k2 = 0; k2 < 2; ++k2) {
    if (k2) __syncthreads();
    for (int fi = t; fi < 1024; fi += 256) {
      int row = fi >> 4, c8 = fi & 15;
      *(uint4*)&As[row * 136 + c8 * 8] =
          ((const uint4*)ff)[(size_t)(mbase + row) * 32 + k2 * 16 + c8];
    }
    for (int fi = t; fi < 2048; fi += 256) {
      int row = fi >> 4, c8 = fi & 15;
      ((uint4*)&Ws[row * 136])[c8] =
          ((const uint4*)(w2B + (size_t)row * 256 + k2 * 128))[c8];
    }
    __syncthreads();
    mma128(As, Ws, (rbase + l15) * 136 + quad * 8, (cbase + l15) * 136 + quad * 8, acc);
  }
  __syncthreads();

  float* Yf = (float*)ldsraw;
  float* p1 = (float*)(ldsraw + 33792);
  float* p2 = (float*)(ldsraw + 34816);
  float* Ms = (float*)(ldsraw + 35840);
  float* Rs = (float*)(ldsraw + 36096);
#pragma unroll
  for (int nt = 0; nt < 4; ++nt) {
    int col = cbase + nt * 16 + l15;
    float bias = b2[col];
#pragma unroll
    for (int mt = 0; mt < 2; ++mt)
#pragma unroll
      for (int r = 0; r < 4; ++r)
        Yf[(rbase + mt * 16 + quad * 4 + r) * 132 + col] = acc[mt][nt][r] + bias;
  }
  __syncthreads();
  for (int fi = t; fi < 1024; fi += 256) {
    int row = fi >> 4, c8 = fi & 15;
    uint4 xv = ((const uint4*)hres)[(size_t)(mbase + row) * 16 + c8];
    float* yp = &Yf[row * 132 + c8 * 8];
    float a, b;
    unpack2(xv.x, a, b); yp[0] += a; yp[1] += b;
    unpack2(xv.y, a, b); yp[2] += a; yp[3] += b;
    unpack2(xv.z, a, b); yp[4] += a; yp[5] += b;
    unpack2(xv.w, a, b); yp[6] += a; yp[7] += b;
  }
  __syncthreads();
  {
    int r = t & 63, g = t >> 6;
    float s = 0.f, s2 = 0.f;
    for (int c = g * 32; c < g * 32 + 32; ++c) { float v = Yf[r * 132 + c]; s += v; s2 += v * v; }
    p1[g * 64 + r] = s; p2[g * 64 + r] = s2;
  }
  __syncthreads();
  if (t < 64) {
    float s = p1[t] + p1[64 + t] + p1[128 + t] + p1[192 + t];
    float s2 = p2[t] + p2[64 + t] + p2[128 + t] + p2[192 + t];
    float m = s * (1.f / 128.f);
    float var = s2 * (1.f / 128.f) - m * m;
    Ms[t] = m; Rs[t] = rsqrtf(var + 1e-5f);
  }
  __syncthreads();
  for (int fi = t; fi < 1024; fi += 256) {
    int row = fi >> 4, c8 = fi & 15;
    float m = Ms[row], rr = Rs[row];
    const float* yp = &Yf[row * 132 + c8 * 8];
    uint4 ov;
    float v0, v1;
#define LNPAIR(J, FLD) \
    v0 = (yp[2*J] - m) * rr * lnw[c8*8+2*J] + lnb[c8*8+2*J]; \
    v1 = (yp[2*J+1] - m) * rr * lnw[c8*8+2*J+1] + lnb[c8*8+2*J+1]; \
    ov.FLD = pack2(v0, v1);
    LNPAIR(0, x) LNPAIR(1, y) LNPAIR(2, z) LNPAIR(3, w)
#undef LNPAIR
    ((uint4*)xout)[(size_t)(mbase + row) * 16 + c8] = ov;
  }
}

// ---------------------------------------------------------------------------
__global__ void idx_init_kernel(int* __restrict__ idxmap) {
  int i = blockIdx.x * 256 + threadIdx.x;
  if (i < 2 * HWPIX) idxmap[i] = -1;
}

__global__ void scatter_kernel(const int* __restrict__ coors, int* __restrict__ idxmap) {
  int i = blockIdx.x * 256 + threadIdx.x;
  if (i >= NVOX) return;
  int b = coors[i * 4 + 0], y = coors[i * 4 + 2], xx = coors[i * 4 + 3];
  atomicMax(&idxmap[b * HWPIX + y * 320 + xx], i);
}

// writes PADDED canvas [b][322][322][128]; halo cells = 0
__global__ void canvas_kernel(const unsigned short* __restrict__ x,
                              const int* __restrict__ idxmap,
                              unsigned short* __restrict__ canvas) {
  int idx = blockIdx.x * 256 + threadIdx.x;
  if (idx >= 2 * PCELLS * 16) return;
  int cell = idx >> 4, c8 = idx & 15;
  int b = (cell >= PCELLS) ? 1 : 0;
  cell -= b * PCELLS;
  int yy = cell / PW, xx = cell - yy * PW;
  uint4 v = {0u, 0u, 0u, 0u};
  if (yy >= 1 && yy <= 320 && xx >= 1 && xx <= 320) {
    int vox = idxmap[b * HWPIX + (yy - 1) * 320 + (xx - 1)];
    if (vox >= 0) v = ((const uint4*)x)[(size_t)vox * 16 + c8];
  }
  ((uint4*)canvas)[idx] = v;
}

// zero the halo cells of a padded NHWC buffer (for c1out between the convs)
__global__ void border_kernel(unsigned short* __restrict__ buf) {
  int i = blockIdx.x * 256 + threadIdx.x;
  if (i >= 2 * 1284 * 16) return;
  int c8 = i & 15, j = i >> 4;
  int b = (j >= 1284) ? 1 : 0;
  j -= b * 1284;
  int cell;
  if (j < 322) cell = j;                                   // top row
  else if (j < 644) cell = 321 * PW + (j - 322);           // bottom row
  else { int j2 = j - 644; cell = (1 + (j2 >> 1)) * PW + (j2 & 1) * 321; }  // sides
  uint4 z = {0u, 0u, 0u, 0u};
  ((uint4*)buf)[((size_t)b * PCELLS + cell) * 16 + c8] = z;
}

// ---------------------------------------------------------------------------
// Conv 3x3, padded NHWC bf16 input [b][322][322][128].
// Round-0 structure (M=64 px x N=128 co, patch+weights in LDS, 52.8 KB,
// 3 blocks/CU) + T14 issue-early/write-late staging within each tap.
// CRITICAL: tap loop is `#pragma unroll 1`. With full unroll the scheduler
// hoisted many iterations' prefetch loads, ballooned the live set, and the
// allocator spilled ~900 MB/dispatch to scratch (rounds 2-3: VGPR_Count 72/68,
// WRITE_SIZE ~1 GB). A real backedge bounds the live set to one iteration
// (~115 VGPR) -- the prefetch then actually lands in registers.
template <int NCHW_OUT>
__global__ __launch_bounds__(256, 3) void conv_kernel(
    const unsigned short* __restrict__ in, const unsigned short* __restrict__ wTb,
    void* __restrict__ outp) {
  __shared__ __align__(16) char ldsraw[52768];
  short* patch = (short*)ldsraw;           // [66 cols][136]
  short* Wt = (short*)(ldsraw + 17952);    // [128 co][136]
  const int t = threadIdx.x;
  const int lane = t & 63, wv = t >> 6;
  const int l15 = lane & 15, quad = lane >> 4;
  const int rbase = 32 * (wv >> 1), cbase = 64 * (wv & 1);
  const int x0 = blockIdx.x * 64;
  const int y0 = blockIdx.y;               // output row, padded row = y0+1
  const int b = blockIdx.z;
  const unsigned short* inb = in + (size_t)b * PCELLS * 128;
  const int srow = t >> 4, sc8 = t & 15;   // weight staging coords

  f32x4 acc[2][4];
#pragma unroll
  for (int m = 0; m < 2; ++m)
#pragma unroll
    for (int n = 0; n < 4; ++n) acc[m][n] = (f32x4){0.f, 0.f, 0.f, 0.f};

  uint4 wreg[8];
  uint4 pp[4], px4;

  // --- prologue: load patch(dy=0) + weights(tap=0), write, one barrier ---
  {
    const uint4* src = (const uint4*)inb + ((size_t)y0 * PW + x0) * 16;
#pragma unroll
    for (int k = 0; k < 4; ++k) pp[k] = src[t + 256 * k];
    if (t < 32) px4 = src[1024 + t];
  }
#pragma unroll
  for (int i = 0; i < 8; ++i)
    wreg[i] = ((const uint4*)(wTb + (size_t)(i * 16 + srow) * 128))[sc8];
#pragma unroll
  for (int k = 0; k < 4; ++k) {
    int e = t + 256 * k;
    *(uint4*)&patch[(e >> 4) * 136 + (e & 15) * 8] = pp[k];
  }
  if (t < 32) { int e = 1024 + t; *(uint4*)&patch[(e >> 4) * 136 + (e & 15) * 8] = px4; }
#pragma unroll
  for (int i = 0; i < 8; ++i)
    *(uint4*)&Wt[(i * 16 + srow) * 136 + sc8 * 8] = wreg[i];
  __syncthreads();

#pragma unroll 1
  for (int tap = 0; tap < 9; ++tap) {
    const int dy = tap / 3, dx = tap - dy * 3;
    const bool pfP = (dx == 2) && (dy < 2);   // prefetch patch for dy+1
    const bool pfW = (tap < 8);               // prefetch weights for tap+1
    if (pfP) {
      const uint4* src = (const uint4*)inb + ((size_t)(y0 + dy + 1) * PW + x0) * 16;
#pragma unroll
      for (int k = 0; k < 4; ++k) pp[k] = src[t + 256 * k];
      if (t < 32) px4 = src[1024 + t];
    }
    if (pfW) {
#pragma unroll
      for (int i = 0; i < 8; ++i)
        wreg[i] = ((const uint4*)(wTb + (size_t)((tap + 1) * 128 + i * 16 + srow) * 128))[sc8];
    }
    mma128(patch, Wt, (rbase + l15 + dx) * 136 + quad * 8,
           (cbase + l15) * 136 + quad * 8, acc);
    __syncthreads();   // all waves done reading current LDS contents
    if (pfW) {
      if (pfP) {
#pragma unroll
        for (int k = 0; k < 4; ++k) {
          int e = t + 256 * k;
          *(uint4*)&patch[(e >> 4) * 136 + (e & 15) * 8] = pp[k];
        }
        if (t < 32) { int e = 1024 + t; *(uint4*)&patch[(e >> 4) * 136 + (e & 15) * 8] = px4; }
      }
#pragma unroll
      for (int i = 0; i < 8; ++i)
        *(uint4*)&Wt[(i * 16 + srow) * 136 + sc8 * 8] = wreg[i];
      __syncthreads();
    }
  }
  // last loop iteration ends with a barrier (post-MFMA) -> LDS reuse safe

  if (NCHW_OUT) {
    float* Yf = (float*)ldsraw;  // [128 co][68 px]
#pragma unroll
    for (int nt = 0; nt < 4; ++nt) {
      int col = cbase + nt * 16 + l15;
#pragma unroll
      for (int mt = 0; mt < 2; ++mt)
#pragma unroll
        for (int r = 0; r < 4; ++r)
          Yf[col * 68 + rbase + mt * 16 + quad * 4 + r] = fmaxf(acc[mt][nt][r], 0.f);
    }
    __syncthreads();
    float* out = (float*)outp;
    for (int fi = t; fi < 2048; fi += 256) {
      int co = fi >> 4, q4 = fi & 15;
      float4 v = *(float4*)&Yf[co * 68 + q4 * 4];
      *(float4*)&out[(size_t)(b * 128 + co) * HWPIX + y0 * 320 + x0 + q4 * 4] = v;
    }
  } else {
    short* Ybf = (short*)ldsraw;  // [64 px][136 co]
#pragma unroll
    for (int nt = 0; nt < 4; ++nt) {
      int col = cbase + nt * 16 + l15;
#pragma unroll
      for (int mt = 0; mt < 2; ++mt)
#pragma unroll
        for (int r = 0; r < 4; ++r)
          Ybf[(rbase + mt * 16 + quad * 4 + r) * 136 + col] =
              (short)f2bf(fmaxf(acc[mt][nt][r], 0.f));
    }
    __syncthreads();
    unsigned short* out = (unsigned short*)outp;
    for (int fi = t; fi < 1024; fi += 256) {
      int row = fi >> 4, c8 = fi & 15;
      ((uint4*)out)[((size_t)b * PCELLS + (size_t)(y0 + 1) * PW + x0 + 1 + row) * 16 + c8] =
          ((const uint4*)&Ybf[row * 136])[c8];
    }
  }
}

// ============================================================================
extern "C" void kernel_launch(void* const* d_in, const int* in_sizes, int n_in,
                              void* d_out, int out_size, void* d_ws, size_t ws_size,
                              hipStream_t stream) {
  const float* voxel_feats = (const float*)d_in[0];
  const float* pos0 = (const float*)d_in[1];
  const float* pos1 = (const float*)d_in[2];
  const float* ipw = (const float*)d_in[3];
  const float* ipb = (const float*)d_in[4];
  const float* opw = (const float*)d_in[5];
  const float* opb = (const float*)d_in[6];
  const float* l1w = (const float*)d_in[7];
  const float* l1b = (const float*)d_in[8];
  const float* l2w = (const float*)d_in[9];
  const float* l2b = (const float*)d_in[10];
  const float* n1w = (const float*)d_in[11];
  const float* n1b = (const float*)d_in[12];
  const float* n2w = (const float*)d_in[13];
  const float* n2b = (const float*)d_in[14];
  const float* convw = (const float*)d_in[15];
  const int* coors = (const int*)d_in[16];
  const int* ind0 = (const int*)d_in[17];
  const int* ind1 = (const int*)d_in[18];

  unsigned short* ws = (unsigned short*)d_ws;
  const size_t NC = (size_t)NVOX * CDIM;  // 15,360,000
  unsigned short* bx = ws;
  unsigned short* bq = ws + NC;
  unsigned short* bk = ws + 2 * NC;
  unsigned short* bv = ws + 3 * NC;
  unsigned short* bh = ws + 4 * NC;
  unsigned short* bff = ws + 5 * NC;       // 2*NC
  unsigned short* wB = ws + 7 * NC;        // 819200 bf16 weights
  unsigned short* ipwB = wB;               // 196608
  unsigned short* opwB = wB + 196608;      // 65536
  unsigned short* l1wB = wB + 262144;      // 131072
  unsigned short* l2wB = wB + 393216;      // 131072
  unsigned short* convB = wB + 524288;     // 294912
  int* idxmap = (int*)(wB + 819200);       // 204800 ints
  unsigned short* canvas = bq;             // padded: 26.54M shorts <= 2*NC (bq..bk)
  unsigned short* c1out = bv;              // padded: 26.54M shorts <= 2*NC (bv..bh)

  cvt_kernel<<<15000, 256, 0, stream>>>(voxel_feats, bx, 3840000);
  cvt_kernel<<<192, 256, 0, stream>>>(ipw, ipwB, 49152);
  cvt_kernel<<<64, 256, 0, stream>>>(opw, opwB, 16384);
  cvt_kernel<<<128, 256, 0, stream>>>(l1w, l1wB, 32768);
  cvt_kernel<<<128, 256, 0, stream>>>(l2w, l2wB, 32768);
  cvtT_kernel<<<1152, 256, 0, stream>>>(convw, convB);

  for (int l = 0; l < 4; ++l) {
    const int* ind = (l & 1) ? ind1 : ind0;
    const float* pos = (l & 1) ? pos1 : pos0;
    qkv_kernel<<<dim3(1875, 3), 256, 0, stream>>>(
        bx, pos, ind, ipwB + (size_t)l * 49152, ipb + l * 384, bq, bk, bv);
    attn_kernel<<<NWIN, 256, 0, stream>>>(bq, bk, bv);
    outln_kernel<<<1875, 256, 0, stream>>>(
        bq, ind, opwB + (size_t)l * 16384, opb + l * 128, bx,
        n1w + l * 128, n1b + l * 128, bh);
    ffn1_kernel<<<dim3(1875, 2), 256, 0, stream>>>(
        bh, l1wB + (size_t)l * 32768, l1b + l * 256, bff);
    ffn2_kernel<<<1875, 256, 0, stream>>>(
        bff, l2wB + (size_t)l * 32768, l2b + l * 128, bh,
        n2w + l * 128, n2b + l * 128, bx);
  }

  idx_init_kernel<<<800, 256, 0, stream>>>(idxmap);
  scatter_kernel<<<(NVOX + 255) / 256, 256, 0, stream>>>(coors, idxmap);
  canvas_kernel<<<(2 * PCELLS * 16 + 255) / 256, 256, 0, stream>>>(bx, idxmap, canvas);
  border_kernel<<<(2 * 1284 * 16 + 255) / 256, 256, 0, stream>>>(c1out);

  conv_kernel<0><<<dim3(5, 320, 2), 256, 0, stream>>>(canvas, convB, (void*)c1out);
  conv_kernel<1><<<dim3(5, 320, 2), 256, 0, stream>>>(c1out, convB + 9 * 16384, d_out);
}

// Round 5
// 1568.238 us; speedup vs baseline: 1.2426x; 1.2399x over previous
//
#include <hip/hip_runtime.h>
#include <math.h>

#define NVOX 120000
#define CDIM 128
#define NWIN 5000
#define HWPIX 102400

typedef __attribute__((ext_vector_type(8))) short short8;
typedef __attribute__((ext_vector_type(4))) float f32x4;

__device__ __forceinline__ unsigned short f2bf(float f) {
  unsigned u = __float_as_uint(f);
  return (unsigned short)((u + 0x7FFFu + ((u >> 16) & 1u)) >> 16);
}
__device__ __forceinline__ unsigned pack2(float a, float b) {
  return (unsigned)f2bf(a) | ((unsigned)f2bf(b) << 16);
}
__device__ __forceinline__ void unpack2(unsigned u, float& a, float& b) {
  a = __uint_as_float(u << 16);
  b = __uint_as_float(u & 0xFFFF0000u);
}

// ============================================================================
// MFMA core: block = 256 thr = 4 waves. Block tile M=64 x N=128, K staged 128.
// Wave wv: rows 32*(wv>>1)+{0..31} (2 m-tiles), cols 64*(wv&1)+{0..63} (4 n-tiles).
// LDS pitch 136 bf16 (272 B -> bank stride 4 mod 32 -> 2-way, free).
// A-frag: A[m=lane&15][k=quad*8+j]; B-frag: W[n=lane&15][k=quad*8+j] (W is [N][K]).
// C/D: col=lane&15, row=quad*4+reg.
// ============================================================================
__device__ __forceinline__ void mma128(const short* __restrict__ As,
                                       const short* __restrict__ Ws,
                                       int aoff, int boff, f32x4 acc[2][4]) {
#pragma unroll
  for (int kc = 0; kc < 4; ++kc) {
    short8 a0 = *(const short8*)(As + aoff + kc * 32);
    short8 a1 = *(const short8*)(As + aoff + 136 * 16 + kc * 32);
#pragma unroll
    for (int nt = 0; nt < 4; ++nt) {
      short8 b = *(const short8*)(Ws + boff + nt * 136 * 16 + kc * 32);
      acc[0][nt] = __builtin_amdgcn_mfma_f32_16x16x32_bf16(a0, b, acc[0][nt], 0, 0, 0);
      acc[1][nt] = __builtin_amdgcn_mfma_f32_16x16x32_bf16(a1, b, acc[1][nt], 0, 0, 0);
    }
  }
}

// ---------------------------------------------------------------------------
__global__ __launch_bounds__(256) void cvt_kernel(const float* __restrict__ src,
                                                  unsigned short* __restrict__ dst, int n4) {
  int i = blockIdx.x * 256 + threadIdx.x;
  if (i >= n4) return;
  float4 v = ((const float4*)src)[i];
  uint2 o; o.x = pack2(v.x, v.y); o.y = pack2(v.z, v.w);
  ((uint2*)dst)[i] = o;
}

__global__ __launch_bounds__(256) void cvtT_kernel(const float* __restrict__ w,
                                                   unsigned short* __restrict__ wT) {
  int idx = blockIdx.x * 256 + threadIdx.x;
  if (idx >= 2 * 9 * 128 * 128) return;
  int ci = idx & 127;
  int co = (idx >> 7) & 127;
  int tap = (idx >> 14) % 9;
  int conv = idx / (9 * 16384);
  wT[idx] = f2bf(w[((size_t)(conv * 128 + co) * 128 + ci) * 9 + tap]);
}

// ---------------------------------------------------------------------------
// FUSED QKV: one dispatch per layer (was 3). Stages the x-tile ONCE; computes
// V first (A = x), then adds pos into the LDS A-tile IN PLACE (same numerics:
// unpack bf16 x, add f32 pos, repack), then computes Q and K from the same A.
// Saves per layer: 2x x-tile reads (61 MB), 1x pos gather (61 MB), 2 launches.
// Y staging reuses the Ws region (barriers both sides). No cross-barrier
// register prefetch (rounds 2-4 showed that pattern spills to scratch).
__global__ __launch_bounds__(256) void qkv_kernel(
    const unsigned short* __restrict__ x, const float* __restrict__ pos,
    const int* __restrict__ ind, const unsigned short* __restrict__ ipwB,
    const float* __restrict__ ipb, unsigned short* __restrict__ qb,
    unsigned short* __restrict__ kb, unsigned short* __restrict__ vb) {
  __shared__ __align__(16) char ldsraw[52224];
  short* As = (short*)ldsraw;             // [64][136]
  short* Ws = (short*)(ldsraw + 17408);   // [128][136]; also Y staging [64][136]
  const int t = threadIdx.x;
  const int lane = t & 63, wv = t >> 6;
  const int l15 = lane & 15, quad = lane >> 4;
  const int rbase = 32 * (wv >> 1), cbase = 64 * (wv & 1);
  const int mbase = blockIdx.x * 64;
  const int aoff = (rbase + l15) * 136 + quad * 8;
  const int boff = (cbase + l15) * 136 + quad * 8;

  // ---- phase 0: stage A = x (no pos), W = Wv (rows 256..383) ----
  for (int fi = t; fi < 1024; fi += 256) {
    int row = fi >> 4, c8 = fi & 15;
    *(uint4*)&As[row * 136 + c8 * 8] =
        ((const uint4*)x)[(size_t)(mbase + row) * 16 + c8];
  }
  for (int fi = t; fi < 2048; fi += 256) {
    int row = fi >> 4, c8 = fi & 15;
    ((uint4*)&Ws[row * 136])[c8] =
        ((const uint4*)(ipwB + (size_t)(256 + row) * 128))[c8];
  }
  __syncthreads();

  // ---- V matmul ----
  {
    f32x4 acc[2][4];
#pragma unroll
    for (int m = 0; m < 2; ++m)
#pragma unroll
      for (int n = 0; n < 4; ++n) acc[m][n] = (f32x4){0.f, 0.f, 0.f, 0.f};
    mma128(As, Ws, aoff, boff, acc);
    __syncthreads();   // done reading As & Ws

    // V epilogue -> Ybf (Ws region); concurrently add pos into As in place
    short* Ybf = Ws;
#pragma unroll
    for (int nt = 0; nt < 4; ++nt) {
      int col = cbase + nt * 16 + l15;
      float bias = ipb[256 + col];
#pragma unroll
      for (int mt = 0; mt < 2; ++mt)
#pragma unroll
        for (int r = 0; r < 4; ++r)
          Ybf[(rbase + mt * 16 + quad * 4 + r) * 136 + col] =
              (short)f2bf(acc[mt][nt][r] + bias);
    }
    for (int fi = t; fi < 1024; fi += 256) {
      int row = fi >> 4, c8 = fi & 15;
      int s = ind[mbase + row];
      const float4* pp = (const float4*)(pos + (size_t)s * 128 + c8 * 8);
      float4 p0 = pp[0], p1 = pp[1];
      uint4 xv = *(const uint4*)&As[row * 136 + c8 * 8];
      float f0, f1, f2, f3, f4, f5, f6, f7;
      unpack2(xv.x, f0, f1); unpack2(xv.y, f2, f3);
      unpack2(xv.z, f4, f5); unpack2(xv.w, f6, f7);
      xv.x = pack2(f0 + p0.x, f1 + p0.y); xv.y = pack2(f2 + p0.z, f3 + p0.w);
      xv.z = pack2(f4 + p1.x, f5 + p1.y); xv.w = pack2(f6 + p1.z, f7 + p1.w);
      *(uint4*)&As[row * 136 + c8 * 8] = xv;
    }
    __syncthreads();

    // copy V out (slot mapping)
    for (int fi = t; fi < 1024; fi += 256) {
      int row = fi >> 4, c8 = fi & 15;
      int s = ind[mbase + row];
      int slot = (s / 36) * 24 + (s % 36);
      ((uint4*)vb)[(size_t)slot * 16 + c8] = ((const uint4*)&Ybf[row * 136])[c8];
    }
    __syncthreads();   // Ybf (Ws region) free for next W staging
  }

  // ---- Q (sec 0) then K (sec 1) against the pos-added A ----
  for (int sec = 0; sec < 2; ++sec) {
    for (int fi = t; fi < 2048; fi += 256) {
      int row = fi >> 4, c8 = fi & 15;
      ((uint4*)&Ws[row * 136])[c8] =
          ((const uint4*)(ipwB + (size_t)(sec * 128 + row) * 128))[c8];
    }
    __syncthreads();
    f32x4 acc[2][4];
#pragma unroll
    for (int m = 0; m < 2; ++m)
#pragma unroll
      for (int n = 0; n < 4; ++n) acc[m][n] = (f32x4){0.f, 0.f, 0.f, 0.f};
    mma128(As, Ws, aoff, boff, acc);
    __syncthreads();

    short* Ybf = Ws;
#pragma unroll
    for (int nt = 0; nt < 4; ++nt) {
      int col = cbase + nt * 16 + l15;
      float bias = ipb[sec * 128 + col];
#pragma unroll
      for (int mt = 0; mt < 2; ++mt)
#pragma unroll
        for (int r = 0; r < 4; ++r)
          Ybf[(rbase + mt * 16 + quad * 4 + r) * 136 + col] =
              (short)f2bf(acc[mt][nt][r] + bias);
    }
    __syncthreads();
    unsigned short* dst = (sec == 0) ? qb : kb;
    for (int fi = t; fi < 1024; fi += 256) {
      int row = fi >> 4, c8 = fi & 15;
      int s = ind[mbase + row];
      int slot = (s / 36) * 24 + (s % 36);
      ((uint4*)dst)[(size_t)slot * 16 + c8] = ((const uint4*)&Ybf[row * 136])[c8];
    }
    __syncthreads();
  }
}

// ---------------------------------------------------------------------------
__global__ __launch_bounds__(256) void attn_kernel(
    unsigned short* __restrict__ qb, const unsigned short* __restrict__ kb,
    const unsigned short* __restrict__ vb) {
  __shared__ float lds[14112];
  float* Qs = lds;          // [24][132]
  float* Ks = lds + 3168;
  float* Vs = lds + 6336;
  float* S = lds + 9504;    // [8][24][24]
  const int t = threadIdx.x;
  const size_t base = (size_t)blockIdx.x * 3072;
  for (int fi = t; fi < 1152; fi += 256) {
    int arr = fi / 384, rem = fi % 384;
    int row = rem >> 4, c8 = rem & 15;
    const unsigned short* src = arr == 0 ? qb : (arr == 1 ? kb : vb);
    uint4 raw = ((const uint4*)(src + base))[row * 16 + c8];
    float* dl = lds + arr * 3168 + row * 132 + c8 * 8;
    unpack2(raw.x, dl[0], dl[1]); unpack2(raw.y, dl[2], dl[3]);
    unpack2(raw.z, dl[4], dl[5]); unpack2(raw.w, dl[6], dl[7]);
  }
  __syncthreads();
  for (int idx = t; idx < 4608; idx += 256) {
    int hh = idx / 576, rem = idx % 576;
    int qq = rem / 24, kk = rem % 24;
    const float* qp = &Qs[qq * 132 + hh * 16];
    const float* kp = &Ks[kk * 132 + hh * 16];
    float s = 0.f;
#pragma unroll
    for (int d = 0; d < 16; ++d) s = fmaf(qp[d], kp[d], s);
    S[idx] = s * 0.25f;
  }
  __syncthreads();
  if (t < 192) {
    float* rowp = &S[t * 24];
    float m = rowp[0];
#pragma unroll
    for (int k2 = 1; k2 < 24; ++k2) m = fmaxf(m, rowp[k2]);
    float sum = 0.f;
#pragma unroll
    for (int k2 = 0; k2 < 24; ++k2) { float e = __expf(rowp[k2] - m); rowp[k2] = e; sum += e; }
    float inv = 1.f / sum;
#pragma unroll
    for (int k2 = 0; k2 < 24; ++k2) rowp[k2] *= inv;
  }
  __syncthreads();
  for (int idx = t; idx < 3072; idx += 256) {
    int hh = idx / 384, rem = idx % 384;
    int qq = rem >> 4, dd = rem & 15;
    const float* pp = &S[hh * 576 + qq * 24];
    const float* vp = &Vs[hh * 16 + dd];
    float o = 0.f;
#pragma unroll
    for (int k2 = 0; k2 < 24; ++k2) o = fmaf(pp[k2], vp[k2 * 132], o);
    qb[base + qq * 128 + hh * 16 + dd] = f2bf(o);
  }
}

// ---------------------------------------------------------------------------
__global__ __launch_bounds__(256) void outln_kernel(
    const unsigned short* __restrict__ o, const int* __restrict__ ind,
    const unsigned short* __restrict__ opwB, const float* __restrict__ opb,
    const unsigned short* __restrict__ xres, const float* __restrict__ lnw,
    const float* __restrict__ lnb, unsigned short* __restrict__ hout) {
  __shared__ __align__(16) char ldsraw[52224];
  short* As = (short*)ldsraw;
  short* Ws = (short*)(ldsraw + 17408);
  const int t = threadIdx.x;
  const int lane = t & 63, wv = t >> 6;
  const int l15 = lane & 15, quad = lane >> 4;
  const int rbase = 32 * (wv >> 1), cbase = 64 * (wv & 1);
  const int mbase = blockIdx.x * 64;
  f32x4 acc[2][4];
#pragma unroll
  for (int m = 0; m < 2; ++m)
#pragma unroll
    for (int n = 0; n < 4; ++n) acc[m][n] = (f32x4){0.f, 0.f, 0.f, 0.f};

  for (int fi = t; fi < 1024; fi += 256) {
    int row = fi >> 4, c8 = fi & 15;
    int s = ind[mbase + row];
    int slot = (s / 36) * 24 + (s % 36);
    *(uint4*)&As[row * 136 + c8 * 8] = ((const uint4*)o)[(size_t)slot * 16 + c8];
  }
  for (int fi = t; fi < 2048; fi += 256) {
    int row = fi >> 4, c8 = fi & 15;
    ((uint4*)&Ws[row * 136])[c8] = ((const uint4*)(opwB + (size_t)row * 128))[c8];
  }
  __syncthreads();
  mma128(As, Ws, (rbase + l15) * 136 + quad * 8, (cbase + l15) * 136 + quad * 8, acc);
  __syncthreads();

  float* Yf = (float*)ldsraw;               // [64][132]
  float* p1 = (float*)(ldsraw + 33792);
  float* p2 = (float*)(ldsraw + 34816);
  float* Ms = (float*)(ldsraw + 35840);
  float* Rs = (float*)(ldsraw + 36096);
#pragma unroll
  for (int nt = 0; nt < 4; ++nt) {
    int col = cbase + nt * 16 + l15;
    float bias = opb[col];
#pragma unroll
    for (int mt = 0; mt < 2; ++mt)
#pragma unroll
      for (int r = 0; r < 4; ++r)
        Yf[(rbase + mt * 16 + quad * 4 + r) * 132 + col] = acc[mt][nt][r] + bias;
  }
  __syncthreads();
  for (int fi = t; fi < 1024; fi += 256) {
    int row = fi >> 4, c8 = fi & 15;
    uint4 xv = ((const uint4*)xres)[(size_t)(mbase + row) * 16 + c8];
    float* yp = &Yf[row * 132 + c8 * 8];
    float a, b;
    unpack2(xv.x, a, b); yp[0] += a; yp[1] += b;
    unpack2(xv.y, a, b); yp[2] += a; yp[3] += b;
    unpack2(xv.z, a, b); yp[4] += a; yp[5] += b;
    unpack2(xv.w, a, b); yp[6] += a; yp[7] += b;
  }
  __syncthreads();
  {
    int r = t & 63, g = t >> 6;
    float s = 0.f, s2 = 0.f;
    for (int c = g * 32; c < g * 32 + 32; ++c) { float v = Yf[r * 132 + c]; s += v; s2 += v * v; }
    p1[g * 64 + r] = s; p2[g * 64 + r] = s2;
  }
  __syncthreads();
  if (t < 64) {
    float s = p1[t] + p1[64 + t] + p1[128 + t] + p1[192 + t];
    float s2 = p2[t] + p2[64 + t] + p2[128 + t] + p2[192 + t];
    float m = s * (1.f / 128.f);
    float var = s2 * (1.f / 128.f) - m * m;
    Ms[t] = m; Rs[t] = rsqrtf(var + 1e-5f);
  }
  __syncthreads();
  for (int fi = t; fi < 1024; fi += 256) {
    int row = fi >> 4, c8 = fi & 15;
    float m = Ms[row], rr = Rs[row];
    const float* yp = &Yf[row * 132 + c8 * 8];
    uint4 ov;
    float v0, v1;
#define LNPAIR(J, FLD) \
    v0 = (yp[2*J] - m) * rr * lnw[c8*8+2*J] + lnb[c8*8+2*J]; \
    v1 = (yp[2*J+1] - m) * rr * lnw[c8*8+2*J+1] + lnb[c8*8+2*J+1]; \
    ov.FLD = pack2(v0, v1);
    LNPAIR(0, x) LNPAIR(1, y) LNPAIR(2, z) LNPAIR(3, w)
#undef LNPAIR
    ((uint4*)hout)[(size_t)(mbase + row) * 16 + c8] = ov;
  }
}

// ---------------------------------------------------------------------------
__global__ __launch_bounds__(256) void ffn1_kernel(
    const unsigned short* __restrict__ h, const unsigned short* __restrict__ w1B,
    const float* __restrict__ b1, unsigned short* __restrict__ ff) {
  __shared__ __align__(16) char ldsraw[52224];
  short* As = (short*)ldsraw;
  short* Ws = (short*)(ldsraw + 17408);
  const int t = threadIdx.x;
  const int lane = t & 63, wv = t >> 6;
  const int l15 = lane & 15, quad = lane >> 4;
  const int rbase = 32 * (wv >> 1), cbase = 64 * (wv & 1);
  const int mbase = blockIdx.x * 64;
  const int by = blockIdx.y;
  f32x4 acc[2][4];
#pragma unroll
  for (int m = 0; m < 2; ++m)
#pragma unroll
    for (int n = 0; n < 4; ++n) acc[m][n] = (f32x4){0.f, 0.f, 0.f, 0.f};

  for (int fi = t; fi < 1024; fi += 256) {
    int row = fi >> 4, c8 = fi & 15;
    *(uint4*)&As[row * 136 + c8 * 8] = ((const uint4*)h)[(size_t)(mbase + row) * 16 + c8];
  }
  for (int fi = t; fi < 2048; fi += 256) {
    int row = fi >> 4, c8 = fi & 15;
    ((uint4*)&Ws[row * 136])[c8] =
        ((const uint4*)(w1B + (size_t)(by * 128 + row) * 128))[c8];
  }
  __syncthreads();
  mma128(As, Ws, (rbase + l15) * 136 + quad * 8, (cbase + l15) * 136 + quad * 8, acc);
  __syncthreads();

  short* Ybf = (short*)ldsraw;
#pragma unroll
  for (int nt = 0; nt < 4; ++nt) {
    int col = cbase + nt * 16 + l15;
    float bias = b1[by * 128 + col];
#pragma unroll
    for (int mt = 0; mt < 2; ++mt)
#pragma unroll
      for (int r = 0; r < 4; ++r) {
        float v = acc[mt][nt][r] + bias;
        float g = 0.5f * v * (1.f + erff(v * 0.70710678f));
        Ybf[(rbase + mt * 16 + quad * 4 + r) * 136 + col] = (short)f2bf(g);
      }
  }
  __syncthreads();
  for (int fi = t; fi < 1024; fi += 256) {
    int row = fi >> 4, c8 = fi & 15;
    ((uint4*)ff)[(size_t)(mbase + row) * 32 + by * 16 + c8] =
        ((const uint4*)&Ybf[row * 136])[c8];
  }
}

// ---------------------------------------------------------------------------
__global__ __launch_bounds__(256) void ffn2_kernel(
    const unsigned short* __restrict__ ff, const unsigned short* __restrict__ w2B,
    const float* __restrict__ b2, const unsigned short* __restrict__ hres,
    const float* __restrict__ lnw, const float* __restrict__ lnb,
    unsigned short* __restrict__ xout) {
  __shared__ __align__(16) char ldsraw[52224];
  short* As = (short*)ldsraw;
  short* Ws = (short*)(ldsraw + 17408);
  const int t = threadIdx.x;
  const int lane = t & 63, wv = t >> 6;
  const int l15 = lane & 15, quad = lane >> 4;
  const int rbase = 32 * (wv >> 1), cbase = 64 * (wv & 1);
  const int mbase = blockIdx.x * 64;
  f32x4 acc[2][4];
#pragma unroll
  for (int m = 0; m < 2; ++m)
#pragma unroll
    for (int n = 0; n < 4; ++n) acc[m][n] = (f32x4){0.f, 0.f, 0.f, 0.f};

  for (int k2 = 0; k2 < 2; ++k2) {
    if (k2) __syncthreads();
    for (int fi = t; fi < 1024; fi += 256) {
      int row = fi >> 4, c8 = fi & 15;
      *(uint4*)&As[row * 136 + c8 * 8] =
          ((const uint4*)ff)[(size_t)(mbase + row) * 32 + k2 * 16 + c8];
    }
    for (int fi = t; fi < 2048; fi += 256) {
      int row = fi >> 4, c8 = fi & 15;
      ((uint4*)&Ws[row * 136])[c8] =
          ((const uint4*)(w2B + (size_t)row * 256 + k2 * 128))[c8];
    }
    __syncthreads();
    mma128(As, Ws, (rbase + l15) * 136 + quad * 8, (cbase + l15) * 136 + quad * 8, acc);
  }
  __syncthreads();

  float* Yf = (float*)ldsraw;
  float* p1 = (float*)(ldsraw + 33792);
  float* p2 = (float*)(ldsraw + 34816);
  float* Ms = (float*)(ldsraw + 35840);
  float* Rs = (float*)(ldsraw + 36096);
#pragma unroll
  for (int nt = 0; nt < 4; ++nt) {
    int col = cbase + nt * 16 + l15;
    float bias = b2[col];
#pragma unroll
    for (int mt = 0; mt < 2; ++mt)
#pragma unroll
      for (int r = 0; r < 4; ++r)
        Yf[(rbase + mt * 16 + quad * 4 + r) * 132 + col] = acc[mt][nt][r] + bias;
  }
  __syncthreads();
  for (int fi = t; fi < 1024; fi += 256) {
    int row = fi >> 4, c8 = fi & 15;
    uint4 xv = ((const uint4*)hres)[(size_t)(mbase + row) * 16 + c8];
    float* yp = &Yf[row * 132 + c8 * 8];
    float a, b;
    unpack2(xv.x, a, b); yp[0] += a; yp[1] += b;
    unpack2(xv.y, a, b); yp[2] += a; yp[3] += b;
    unpack2(xv.z, a, b); yp[4] += a; yp[5] += b;
    unpack2(xv.w, a, b); yp[6] += a; yp[7] += b;
  }
  __syncthreads();
  {
    int r = t & 63, g = t >> 6;
    float s = 0.f, s2 = 0.f;
    for (int c = g * 32; c < g * 32 + 32; ++c) { float v = Yf[r * 132 + c]; s += v; s2 += v * v; }
    p1[g * 64 + r] = s; p2[g * 64 + r] = s2;
  }
  __syncthreads();
  if (t < 64) {
    float s = p1[t] + p1[64 + t] + p1[128 + t] + p1[192 + t];
    float s2 = p2[t] + p2[64 + t] + p2[128 + t] + p2[192 + t];
    float m = s * (1.f / 128.f);
    float var = s2 * (1.f / 128.f) - m * m;
    Ms[t] = m; Rs[t] = rsqrtf(var + 1e-5f);
  }
  __syncthreads();
  for (int fi = t; fi < 1024; fi += 256) {
    int row = fi >> 4, c8 = fi & 15;
    float m = Ms[row], rr = Rs[row];
    const float* yp = &Yf[row * 132 + c8 * 8];
    uint4 ov;
    float v0, v1;
#define LNPAIR(J, FLD) \
    v0 = (yp[2*J] - m) * rr * lnw[c8*8+2*J] + lnb[c8*8+2*J]; \
    v1 = (yp[2*J+1] - m) * rr * lnw[c8*8+2*J+1] + lnb[c8*8+2*J+1]; \
    ov.FLD = pack2(v0, v1);
    LNPAIR(0, x) LNPAIR(1, y) LNPAIR(2, z) LNPAIR(3, w)
#undef LNPAIR
    ((uint4*)xout)[(size_t)(mbase + row) * 16 + c8] = ov;
  }
}

// ---------------------------------------------------------------------------
__global__ void idx_init_kernel(int* __restrict__ idxmap) {
  int i = blockIdx.x * 256 + threadIdx.x;
  if (i < 2 * HWPIX) idxmap[i] = -1;
}

__global__ void scatter_kernel(const int* __restrict__ coors, int* __restrict__ idxmap) {
  int i = blockIdx.x * 256 + threadIdx.x;
  if (i >= NVOX) return;
  int b = coors[i * 4 + 0], y = coors[i * 4 + 2], xx = coors[i * 4 + 3];
  atomicMax(&idxmap[b * HWPIX + y * 320 + xx], i);
}

__global__ void canvas_kernel(const unsigned short* __restrict__ x,
                              const int* __restrict__ idxmap,
                              unsigned short* __restrict__ canvas) {
  int idx = blockIdx.x * 256 + threadIdx.x;
  if (idx >= 2 * HWPIX * 16) return;
  int cell = idx >> 4, c8 = idx & 15;
  int vox = idxmap[cell];
  uint4 v = {0u, 0u, 0u, 0u};
  if (vox >= 0) v = ((const uint4*)x)[(size_t)vox * 16 + c8];
  ((uint4*)canvas)[idx] = v;
}

// ---------------------------------------------------------------------------
// Conv 3x3 pad 1, NHWC bf16 in. Block: 64 px (row segment) x 128 cout.
// (Round-0 version, verbatim: 145 us/dispatch, VGPR 76, no scratch. The
// register-prefetch variants of rounds 2-4 all spilled ~950 MB/dispatch.)
template <int NCHW_OUT>
__global__ __launch_bounds__(256) void conv_kernel(
    const unsigned short* __restrict__ in, const unsigned short* __restrict__ wTb,
    void* __restrict__ outp) {
  __shared__ __align__(16) char ldsraw[52768];
  short* patch = (short*)ldsraw;           // [66 cols][136 ci]
  short* Wt = (short*)(ldsraw + 17952);    // [128 co][136 ci]
  const int t = threadIdx.x;
  const int lane = t & 63, wv = t >> 6;
  const int l15 = lane & 15, quad = lane >> 4;
  const int rbase = 32 * (wv >> 1), cbase = 64 * (wv & 1);
  const int x0 = blockIdx.x * 64;
  const int y = blockIdx.y;
  const int b = blockIdx.z;
  const unsigned short* inb = in + (size_t)b * HWPIX * 128;
  f32x4 acc[2][4];
#pragma unroll
  for (int m = 0; m < 2; ++m)
#pragma unroll
    for (int n = 0; n < 4; ++n) acc[m][n] = (f32x4){0.f, 0.f, 0.f, 0.f};

  for (int dy = 0; dy < 3; ++dy) {
    __syncthreads();
    int gy = y + dy - 1;
    for (int fi = t; fi < 1056; fi += 256) {
      int col = fi >> 4, c8 = fi & 15;
      int gx = x0 + col - 1;
      uint4 v = {0u, 0u, 0u, 0u};
      if (gy >= 0 && gy < 320 && gx >= 0 && gx < 320)
        v = ((const uint4*)inb)[(size_t)(gy * 320 + gx) * 16 + c8];
      *(uint4*)&patch[col * 136 + c8 * 8] = v;
    }
    for (int dx = 0; dx < 3; ++dx) {
      __syncthreads();
      int tap = dy * 3 + dx;
      for (int fi = t; fi < 2048; fi += 256) {
        int row = fi >> 4, c8 = fi & 15;
        ((uint4*)&Wt[row * 136])[c8] =
            ((const uint4*)(wTb + (size_t)(tap * 128 + row) * 128))[c8];
      }
      __syncthreads();
      mma128(patch, Wt, (rbase + l15 + dx) * 136 + quad * 8,
             (cbase + l15) * 136 + quad * 8, acc);
    }
  }
  __syncthreads();
  if (NCHW_OUT) {
    float* Yf = (float*)ldsraw;  // [128 co][68 px]
#pragma unroll
    for (int nt = 0; nt < 4; ++nt) {
      int col = cbase + nt * 16 + l15;
#pragma unroll
      for (int mt = 0; mt < 2; ++mt)
#pragma unroll
        for (int r = 0; r < 4; ++r)
          Yf[col * 68 + rbase + mt * 16 + quad * 4 + r] = fmaxf(acc[mt][nt][r], 0.f);
    }
    __syncthreads();
    float* out = (float*)outp;
    for (int fi = t; fi < 2048; fi += 256) {
      int co = fi >> 4, q4 = fi & 15;
      float4 v = *(float4*)&Yf[co * 68 + q4 * 4];
      *(float4*)&out[(size_t)(b * 128 + co) * HWPIX + y * 320 + x0 + q4 * 4] = v;
    }
  } else {
    short* Ybf = (short*)ldsraw;  // [64 px][136 co]
#pragma unroll
    for (int nt = 0; nt < 4; ++nt) {
      int col = cbase + nt * 16 + l15;
#pragma unroll
      for (int mt = 0; mt < 2; ++mt)
#pragma unroll
        for (int r = 0; r < 4; ++r)
          Ybf[(rbase + mt * 16 + quad * 4 + r) * 136 + col] =
              (short)f2bf(fmaxf(acc[mt][nt][r], 0.f));
    }
    __syncthreads();
    unsigned short* out = (unsigned short*)outp;
    for (int fi = t; fi < 1024; fi += 256) {
      int row = fi >> 4, c8 = fi & 15;
      ((uint4*)out)[((size_t)b * HWPIX + y * 320 + x0 + row) * 16 + c8] =
          ((const uint4*)&Ybf[row * 136])[c8];
    }
  }
}

// ============================================================================
extern "C" void kernel_launch(void* const* d_in, const int* in_sizes, int n_in,
                              void* d_out, int out_size, void* d_ws, size_t ws_size,
                              hipStream_t stream) {
  const float* voxel_feats = (const float*)d_in[0];
  const float* pos0 = (const float*)d_in[1];
  const float* pos1 = (const float*)d_in[2];
  const float* ipw = (const float*)d_in[3];
  const float* ipb = (const float*)d_in[4];
  const float* opw = (const float*)d_in[5];
  const float* opb = (const float*)d_in[6];
  const float* l1w = (const float*)d_in[7];
  const float* l1b = (const float*)d_in[8];
  const float* l2w = (const float*)d_in[9];
  const float* l2b = (const float*)d_in[10];
  const float* n1w = (const float*)d_in[11];
  const float* n1b = (const float*)d_in[12];
  const float* n2w = (const float*)d_in[13];
  const float* n2b = (const float*)d_in[14];
  const float* convw = (const float*)d_in[15];
  const int* coors = (const int*)d_in[16];
  const int* ind0 = (const int*)d_in[17];
  const int* ind1 = (const int*)d_in[18];

  unsigned short* ws = (unsigned short*)d_ws;
  const size_t NC = (size_t)NVOX * CDIM;  // 15,360,000
  unsigned short* bx = ws;
  unsigned short* bq = ws + NC;
  unsigned short* bk = ws + 2 * NC;
  unsigned short* bv = ws + 3 * NC;
  unsigned short* bh = ws + 4 * NC;
  unsigned short* bff = ws + 5 * NC;       // 2*NC
  unsigned short* wB = ws + 7 * NC;        // 819200 bf16 weights
  unsigned short* ipwB = wB;               // 196608
  unsigned short* opwB = wB + 196608;      // 65536
  unsigned short* l1wB = wB + 262144;      // 131072
  unsigned short* l2wB = wB + 393216;      // 131072
  unsigned short* convB = wB + 524288;     // 294912
  int* idxmap = (int*)(wB + 819200);       // 204800 ints
  unsigned short* canvas = bq;             // 26.2M <= 2*NC (bq..bk)
  unsigned short* c1out = bv;              // 26.2M <= 2*NC (bv..bh)

  cvt_kernel<<<15000, 256, 0, stream>>>(voxel_feats, bx, 3840000);
  cvt_kernel<<<192, 256, 0, stream>>>(ipw, ipwB, 49152);
  cvt_kernel<<<64, 256, 0, stream>>>(opw, opwB, 16384);
  cvt_kernel<<<128, 256, 0, stream>>>(l1w, l1wB, 32768);
  cvt_kernel<<<128, 256, 0, stream>>>(l2w, l2wB, 32768);
  cvtT_kernel<<<1152, 256, 0, stream>>>(convw, convB);

  for (int l = 0; l < 4; ++l) {
    const int* ind = (l & 1) ? ind1 : ind0;
    const float* pos = (l & 1) ? pos1 : pos0;
    qkv_kernel<<<1875, 256, 0, stream>>>(
        bx, pos, ind, ipwB + (size_t)l * 49152, ipb + l * 384, bq, bk, bv);
    attn_kernel<<<NWIN, 256, 0, stream>>>(bq, bk, bv);
    outln_kernel<<<1875, 256, 0, stream>>>(
        bq, ind, opwB + (size_t)l * 16384, opb + l * 128, bx,
        n1w + l * 128, n1b + l * 128, bh);
    ffn1_kernel<<<dim3(1875, 2), 256, 0, stream>>>(
        bh, l1wB + (size_t)l * 32768, l1b + l * 256, bff);
    ffn2_kernel<<<1875, 256, 0, stream>>>(
        bff, l2wB + (size_t)l * 32768, l2b + l * 128, bh,
        n2w + l * 128, n2b + l * 128, bx);
  }

  idx_init_kernel<<<800, 256, 0, stream>>>(idxmap);
  scatter_kernel<<<(NVOX + 255) / 256, 256, 0, stream>>>(coors, idxmap);
  canvas_kernel<<<12800, 256, 0, stream>>>(bx, idxmap, canvas);

  conv_kernel<0><<<dim3(5, 320, 2), 256, 0, stream>>>(canvas, convB, (void*)c1out);
  conv_kernel<1><<<dim3(5, 320, 2), 256, 0, stream>>>(c1out, convB + 9 * 16384, d_out);
}